// Round 6
// baseline (561.850 us; speedup 1.0000x reference)
//
#include <hip/hip_runtime.h>
#include <hip/hip_bf16.h>
#include <math.h>

typedef __bf16 bf16x8 __attribute__((ext_vector_type(8)));
typedef float floatx4 __attribute__((ext_vector_type(4)));
typedef unsigned short ushort8 __attribute__((ext_vector_type(8)));
typedef unsigned short ushort4v __attribute__((ext_vector_type(4)));

__device__ __forceinline__ unsigned short f2bs(float f){
  union { float f; unsigned u; } v; v.f = f;
  unsigned r = v.u + 0x7fffu + ((v.u >> 16) & 1u);
  return (unsigned short)(r >> 16);
}
__device__ __forceinline__ float bs2f(unsigned short s){
  union { unsigned u; float f; } v; v.u = ((unsigned)s) << 16; return v.f;
}
// packed f32x2 -> bf16x2 (RNE)
__device__ __forceinline__ unsigned pk2(float a, float b){
  union { __hip_bfloat162 h; unsigned u; } cv;
  cv.h = __float22bfloat162_rn(make_float2(a, b));
  return cv.u;
}
__device__ __forceinline__ void gl_lds16(const void* g, void* l){
  __builtin_amdgcn_global_load_lds(
      (const __attribute__((address_space(1))) void*)g,
      (__attribute__((address_space(3))) void*)l,
      16, 0, 0);
}

// ---------------- fused prep: cvt_x + pack_qkv + 3x transpose_pack ----------------
// One launch instead of five (graph inter-dispatch gaps were a suspected
// ~50-100us of the 505us total). Flat 1D grid, whole blocks per path:
//   [0,8192):      x fp32 -> Xb bf16
//   [8192,9728):   pack wq/wk/wv -> Wqkv_t [3072][1024] + bias
//   [9728,10240):  wo  [1024][1024] -> Wot  (bf16 [C][R])
//   [10240,12288): w1  [1024][4096] -> W1t
//   [12288,14336): w2  [4096][1024] -> W2t
__global__ __launch_bounds__(256) void prep(
    const float* __restrict__ x,  unsigned short* __restrict__ Xb,
    const float* __restrict__ wq, const float* __restrict__ wk,
    const float* __restrict__ wv, const float* __restrict__ bq,
    const float* __restrict__ bk, const float* __restrict__ bv,
    unsigned short* __restrict__ Wqkv, float* __restrict__ Bqkv,
    const float* __restrict__ wo, unsigned short* __restrict__ Wot,
    const float* __restrict__ w1, unsigned short* __restrict__ W1t,
    const float* __restrict__ w2, unsigned short* __restrict__ W2t){
  __shared__ float tile[32][65];
  const int blk = blockIdx.x, t = threadIdx.x;

  if (blk < 8192){                       // ---- cvt_x ----
    const int i = (blk*256 + t)*4;
    const float4 v = *(const float4*)(x + i);
    ushort4v u = { f2bs(v.x), f2bs(v.y), f2bs(v.z), f2bs(v.w) };
    *(ushort4v*)(Xb + i) = u;
    return;
  }

  if (blk < 9728){                       // ---- pack_qkv ----
    const int p = blk - 8192;
    const int dt = p & 31, h = (p>>5)&15, sel = p>>9;
    const float* src = (sel==0 ? wq : (sel==1 ? wk : wv)) + (size_t)h*65536;
    const int d0 = dt*32;
    {
      const int r = t >> 3, cc = (t & 7)*8;
      const float* pp = src + (size_t)(d0+r)*64 + cc;
      const float4 v0 = *(const float4*)pp;
      const float4 v1 = *(const float4*)(pp+4);
      tile[r][cc+0]=v0.x; tile[r][cc+1]=v0.y; tile[r][cc+2]=v0.z; tile[r][cc+3]=v0.w;
      tile[r][cc+4]=v1.x; tile[r][cc+5]=v1.y; tile[r][cc+6]=v1.z; tile[r][cc+7]=v1.w;
    }
    __syncthreads();
    const int f = t >> 2, rr = (t & 3)*8;
    ushort8 u;
    #pragma unroll
    for (int j=0;j<8;j++) u[j] = f2bs(tile[rr+j][f]);
    const size_t n = (size_t)sel*1024 + h*64 + f;
    *(ushort8*)(Wqkv + n*1024 + d0 + rr) = u;
    if (dt==0 && t<64){
      const float* bs = (sel==0 ? bq : (sel==1 ? bk : bv)) + h*64;
      Bqkv[sel*1024 + h*64 + t] = bs[t];
    }
    return;
  }

  // ---- transpose_pack (3 matrices) ----
  const float* src; unsigned short* dst; int R, C, bx, by;
  if (blk < 10240){ const int q = blk-9728;  src=wo; dst=Wot; R=1024; C=1024; bx=q&15; by=q>>4; }
  else if (blk < 12288){ const int q = blk-10240; src=w1; dst=W1t; R=1024; C=4096; bx=q&63; by=q>>6; }
  else { const int q = blk-12288; src=w2; dst=W2t; R=4096; C=1024; bx=q&15; by=q>>4; }
  const int r0 = by*32, c0 = bx*64;
  {
    const int r = t >> 3, cc = (t & 7)*8;
    const float* p = src + (size_t)(r0+r)*C + c0 + cc;
    const float4 v0 = *(const float4*)p;
    const float4 v1 = *(const float4*)(p+4);
    tile[r][cc+0]=v0.x; tile[r][cc+1]=v0.y; tile[r][cc+2]=v0.z; tile[r][cc+3]=v0.w;
    tile[r][cc+4]=v1.x; tile[r][cc+5]=v1.y; tile[r][cc+6]=v1.z; tile[r][cc+7]=v1.w;
  }
  __syncthreads();
  const int f = t >> 2, rr = (t & 3)*8;
  ushort8 u;
  #pragma unroll
  for (int j=0;j<8;j++) u[j] = f2bs(tile[rr+j][f]);
  *(ushort8*)(dst + (size_t)(c0+f)*R + r0 + rr) = u;
}

// ---------------- transposed-orientation bf16 GEMM (128^2, kept for Wo) ----------------
template<int MODE>
__global__ __launch_bounds__(256, 4)
void gemm_tn(const unsigned short* __restrict__ A,
             const unsigned short* __restrict__ Bt,
             const float* __restrict__ bias,
             void* __restrict__ out0,
             void* __restrict__ out1,
             void* __restrict__ out2,
             int K, int OW, int klen){
  __shared__ __align__(16) unsigned short As[128*32];
  __shared__ __align__(16) unsigned short Bs[128*32];
  const int tid = threadIdx.x;
  const int wave = tid >> 6, lane = tid & 63;
  const int quad = lane >> 4, l15 = lane & 15;
  const int lin = blockIdx.x;
  const int n0 = (lin & 63) << 7;
  const int m0 = (lin >> 6) << 7;
  const int kz = blockIdx.z;
  const int kbase = kz * klen;
  const int wr = (wave >> 1) << 6, wc = (wave & 1) << 6;

  floatx4 acc[4][4];
  #pragma unroll
  for (int i=0;i<4;i++)
    #pragma unroll
    for (int j=0;j<4;j++) acc[i][j] = (floatx4)0.0f;

  const unsigned short* gA[2];
  const unsigned short* gB[2];
  int lofs[2];
  #pragma unroll
  for (int r2=0;r2<2;r2++){
    const int slot = r2*256 + tid;
    const int rp = slot >> 3, rem = slot & 7;
    const int row = rp*2 + (rem >> 2);
    const int kc = (rem & 3) ^ (rp & 3);
    gA[r2] = A  + (size_t)(m0 + row)*K + kbase + kc*8;
    gB[r2] = Bt + (size_t)(n0 + row)*K + kbase + kc*8;
    lofs[r2] = slot*8;
  }
  int aofs[4], bofs[4];
  #pragma unroll
  for (int t=0;t<4;t++){
    const int ra = wr + t*16 + l15;
    aofs[t] = (ra>>1)*64 + (ra&1)*32 + ((quad ^ ((ra>>1)&3))<<3);
    const int rb = wc + t*16 + l15;
    bofs[t] = (rb>>1)*64 + (rb&1)*32 + ((quad ^ ((rb>>1)&3))<<3);
  }

  for (int k0 = 0; k0 < klen; k0 += 32){
    gl_lds16(gA[0] + k0, As + lofs[0]);
    gl_lds16(gA[1] + k0, As + lofs[1]);
    gl_lds16(gB[0] + k0, Bs + lofs[0]);
    gl_lds16(gB[1] + k0, Bs + lofs[1]);
    __syncthreads();
    bf16x8 af[4];
    #pragma unroll
    for (int t=0;t<4;t++) af[t] = *(const bf16x8*)(&As[aofs[t]]);
    #pragma unroll
    for (int j=0;j<4;j++){
      const bf16x8 bv = *(const bf16x8*)(&Bs[bofs[j]]);
      #pragma unroll
      for (int i=0;i<4;i++)
        acc[i][j] = __builtin_amdgcn_mfma_f32_16x16x32_bf16(af[i], bv, acc[i][j], 0,0,0);
    }
    __syncthreads();
  }

  #pragma unroll
  for (int i=0;i<4;i++){
    const int row0 = m0 + wr + i*16 + quad*4;
    float4 b4 = make_float4(0.f,0.f,0.f,0.f);
    if (MODE != 4 || kz == 0) b4 = *(const float4*)(bias + row0);
    #pragma unroll
    for (int j=0;j<4;j++){
      const int tok = n0 + wc + j*16 + l15;
      float v0 = acc[i][j][0] + b4.x;
      float v1 = acc[i][j][1] + b4.y;
      float v2 = acc[i][j][2] + b4.z;
      float v3 = acc[i][j][3] + b4.w;
      if (MODE == 1){
        float4 o4; o4.x=v0; o4.y=v1; o4.z=v2; o4.w=v3;
        *(float4*)((float*)out0 + (size_t)tok*OW + row0) = o4;
      } else if (MODE == 2){
        float vv[4] = {v0,v1,v2,v3};
        #pragma unroll
        for (int r=0;r<4;r++){
          const float v = vv[r];
          const float u = 0.7978845608f*v*(1.0f + 0.044715f*v*v);
          const float e = __builtin_amdgcn_exp2f(u * 2.885390082f);
          vv[r] = 0.5f*v*(1.0f + (1.0f - 2.0f/(1.0f + e)));
        }
        uint2 pkd = make_uint2(pk2(vv[0], vv[1]), pk2(vv[2], vv[3]));
        *(uint2*)((unsigned short*)out0 + (size_t)tok*4096 + row0) = pkd;
      } else if (MODE == 4){
        uint2 pkd = make_uint2(pk2(v0, v1), pk2(v2, v3));
        unsigned short* o = (unsigned short*)(kz ? out1 : out0);
        *(uint2*)(o + (size_t)tok*1024 + row0) = pkd;
      } else {
        if (row0 < 1024){
          const float s = 0.18033688011112042f;
          uint2 pkd = make_uint2(pk2(v0*s, v1*s), pk2(v2*s, v3*s));
          *(uint2*)((unsigned short*)out0 + (size_t)tok*1024 + row0) = pkd;
        } else if (row0 < 2048){
          uint2 pkd = make_uint2(pk2(v0, v1), pk2(v2, v3));
          *(uint2*)((unsigned short*)out1 + (size_t)tok*1024 + (row0-1024)) = pkd;
        } else {
          uint2 pkd = make_uint2(pk2(v0, v1), pk2(v2, v3));
          *(uint2*)((unsigned short*)out2 + (size_t)tok*1024 + (row0-2048)) = pkd;
        }
      }
    }
  }
}

// ---------------- 256x256 pipelined bf16 GEMM, per-instance schedule ----------------
// (unchanged from R5 — three schedules tested, all within noise of each other;
//  FFN1 pinned at ~29% MfmaUtil by staging feed, not barrier rhythm)
#define VMCNT4 asm volatile("s_waitcnt vmcnt(4)" ::: "memory")
#define VMCNT0 asm volatile("s_waitcnt vmcnt(0)" ::: "memory")
#define TAILW { if (tg < NT-2) VMCNT4; else VMCNT0; }
#define LGKM4 { asm volatile("s_waitcnt lgkmcnt(4)" ::: "memory"); __builtin_amdgcn_sched_barrier(0); }
#define LGKM8 { asm volatile("s_waitcnt lgkmcnt(8)" ::: "memory"); __builtin_amdgcn_sched_barrier(0); }
#define LGKM0 { asm volatile("s_waitcnt lgkmcnt(0)" ::: "memory"); __builtin_amdgcn_sched_barrier(0); }
#define PHASE_SYNC                                                            \
    __builtin_amdgcn_s_barrier();                                             \
    asm volatile("s_waitcnt lgkmcnt(0)" ::: "memory");                        \
    __builtin_amdgcn_sched_barrier(0);

#define STAGE_A(T, H) { const int T_ = (T); if (T_ < NT){                     \
    unsigned short* l_ = lds + (T_&1)*32768 + (H)*8192;                       \
    const int ko_ = kbase + (T_<<6);                                          \
    gl_lds16(srcA##H##_0 + ko_, l_ + ch0*8);                                  \
    gl_lds16(srcA##H##_1 + ko_, l_ + ch1*8); } }
#define STAGE_B(T, H) { const int T_ = (T); if (T_ < NT){                     \
    unsigned short* l_ = lds + (T_&1)*32768 + 16384 + (H)*8192;               \
    const int ko_ = kbase + (T_<<6);                                          \
    gl_lds16(srcB##H##_0 + ko_, l_ + ch0*8);                                  \
    gl_lds16(srcB##H##_1 + ko_, l_ + ch1*8); } }

#define MFMA_Q(AF, BF, MH, NH)                                                \
    __builtin_amdgcn_s_setprio(1);                                            \
    _Pragma("unroll")                                                         \
    for (int k_=0;k_<2;k_++)                                                  \
      _Pragma("unroll")                                                       \
      for (int m_=0;m_<4;m_++)                                                \
        _Pragma("unroll")                                                     \
        for (int n_=0;n_<2;n_++)                                              \
          acc[(MH)*4+m_][(NH)*2+n_] = __builtin_amdgcn_mfma_f32_16x16x32_bf16( \
              AF[m_][k_], BF[n_][k_], acc[(MH)*4+m_][(NH)*2+n_], 0,0,0);      \
    __builtin_amdgcn_s_setprio(0);

#define RD_A(DST, BASE)                                                       \
    _Pragma("unroll")                                                         \
    for (int m_=0;m_<4;m_++)                                                  \
      _Pragma("unroll")                                                       \
      for (int k_=0;k_<2;k_++) DST[m_][k_] = *(const bf16x8*)((BASE) + aoff[m_][k_]);
#define RD_B(DST, BASE)                                                       \
    _Pragma("unroll")                                                         \
    for (int n_=0;n_<2;n_++)                                                  \
      _Pragma("unroll")                                                       \
      for (int k_=0;k_<2;k_++) DST[n_][k_] = *(const bf16x8*)((BASE) + boff[n_][k_]);

template<int MODE, int PIPE>
__global__ __launch_bounds__(512, 2)
void gemm256(const unsigned short* __restrict__ A,
             const unsigned short* __restrict__ Bt,
             const float* __restrict__ bias,
             void* __restrict__ out0,
             void* __restrict__ out1,
             void* __restrict__ out2,
             int K, int klen){
  __shared__ __align__(16) unsigned short lds[65536];   // 128 KiB
  const int tid = threadIdx.x;
  const int wave = tid >> 6, lane = tid & 63;
  const int quad = lane >> 4, l15 = lane & 15;
  const int wm = wave >> 2, wn = wave & 3;
  const int lin = blockIdx.x;
  const int n0 = (lin & 31) << 8;     // token tile (fast dim -> pins XCD)
  const int m0 = (lin >> 5) << 8;     // weight tile
  const int kz = blockIdx.z;
  const int kbase = kz * klen;
  const int NT = klen >> 6;

  const int r0 = tid >> 3;
  const int r1 = r0 + 64;
  const int g0 = (tid & 7) ^ (r0 & 7);
  const int ch0 = tid, ch1 = tid + 512;

  const unsigned short* srcA0_0 = A  + (size_t)(m0 +       r0)*K + g0*8;
  const unsigned short* srcA0_1 = A  + (size_t)(m0 +       r1)*K + g0*8;
  const unsigned short* srcA1_0 = A  + (size_t)(m0 + 128 + r0)*K + g0*8;
  const unsigned short* srcA1_1 = A  + (size_t)(m0 + 128 + r1)*K + g0*8;
  const unsigned short* srcB0_0 = Bt + (size_t)(n0 +       r0)*K + g0*8;
  const unsigned short* srcB0_1 = Bt + (size_t)(n0 +       r1)*K + g0*8;
  const unsigned short* srcB1_0 = Bt + (size_t)(n0 + 128 + r0)*K + g0*8;
  const unsigned short* srcB1_1 = Bt + (size_t)(n0 + 128 + r1)*K + g0*8;

  const int xr = l15 & 7;
  int aoff[4][2], boff[2][2];
  #pragma unroll
  for (int m=0;m<4;m++){
    const int rh = wm*64 + m*16 + l15;
    #pragma unroll
    for (int k=0;k<2;k++)
      aoff[m][k] = rh*64 + (((k*4 + quad) ^ xr) << 3);
  }
  #pragma unroll
  for (int n=0;n<2;n++){
    const int rb = wn*32 + n*16 + l15;
    #pragma unroll
    for (int k=0;k<2;k++)
      boff[n][k] = rb*64 + (((k*4 + quad) ^ xr) << 3);
  }

  floatx4 acc[8][4];
  #pragma unroll
  for (int i=0;i<8;i++)
    #pragma unroll
    for (int j=0;j<4;j++) acc[i][j] = (floatx4)0.0f;

  bf16x8 af0[4][2], af1[4][2], bf0[2][2], bf1[2][2];

  STAGE_B(0,0); STAGE_A(0,0); STAGE_A(0,1); STAGE_B(0,1);
  STAGE_B(1,0); STAGE_A(1,0);
  VMCNT4;
  __builtin_amdgcn_s_barrier();

  if (PIPE == 0){
    for (int tg = 0; tg < NT; ++tg){
      const int d = tg & 1;
      const unsigned short* A0b = lds + d*32768;
      const unsigned short* A1b = A0b + 8192;
      const unsigned short* B0b = lds + d*32768 + 16384;
      const unsigned short* B1b = B0b + 8192;

      RD_A(af0, A0b);
      RD_B(bf0, B0b);
      STAGE_A(tg+1, 1);
      PHASE_SYNC;
      MFMA_Q(af0, bf0, 0, 0);
      __builtin_amdgcn_s_barrier();

      RD_B(bf1, B1b);
      STAGE_B(tg+1, 1);
      PHASE_SYNC;
      MFMA_Q(af0, bf1, 0, 1);
      __builtin_amdgcn_s_barrier();

      RD_A(af1, A1b);
      STAGE_B(tg+2, 0);
      PHASE_SYNC;
      MFMA_Q(af1, bf1, 1, 1);
      __builtin_amdgcn_s_barrier();

      STAGE_A(tg+2, 0);
      PHASE_SYNC;
      MFMA_Q(af1, bf0, 1, 0);
      TAILW;
      __builtin_amdgcn_s_barrier();
    }
  } else {
    RD_A(af0, lds);
    RD_B(bf0, lds + 16384);

    for (int tg = 0; tg < NT; ++tg){
      const int d = tg & 1;
      const unsigned short* A1b = lds + d*32768 + 8192;
      const unsigned short* B1b = lds + d*32768 + 16384 + 8192;

      RD_B(bf1, B1b);
      STAGE_A(tg+1, 1);
      LGKM4;
      MFMA_Q(af0, bf0, 0, 0);

      RD_A(af1, A1b);
      STAGE_B(tg+1, 1);
      LGKM8;
      MFMA_Q(af0, bf1, 0, 1);
      __builtin_amdgcn_s_barrier();

      STAGE_B(tg+2, 0);
      LGKM0;
      MFMA_Q(af1, bf1, 1, 1);

      STAGE_A(tg+2, 0);
      TAILW;
      __builtin_amdgcn_s_barrier();
      {
        const unsigned short* A0n = lds + (d^1)*32768;
        const unsigned short* B0n = A0n + 16384;
        if (tg+1 < NT){ RD_A(af0, A0n); }
        MFMA_Q(af1, bf0, 1, 0);
        if (tg+1 < NT){ RD_B(bf0, B0n); }
      }
    }
  }

  // epilogue
  #pragma unroll
  for (int mh=0; mh<2; mh++){
    #pragma unroll
    for (int m=0; m<4; m++){
      const int row0 = m0 + mh*128 + wm*64 + m*16 + quad*4;
      float4 b4 = make_float4(0.f,0.f,0.f,0.f);
      if (MODE != 4 || kz == 0) b4 = *(const float4*)(bias + row0);
      #pragma unroll
      for (int nh=0; nh<2; nh++){
        #pragma unroll
        for (int n=0; n<2; n++){
          const int tok = n0 + nh*128 + wn*32 + n*16 + l15;
          const floatx4 a = acc[mh*4+m][nh*2+n];
          float v0 = a[0]+b4.x, v1 = a[1]+b4.y, v2 = a[2]+b4.z, v3 = a[3]+b4.w;
          if (MODE == 2){
            float vv[4] = {v0,v1,v2,v3};
            #pragma unroll
            for (int r=0;r<4;r++){
              const float v = vv[r];
              const float u = 0.7978845608f*v*(1.0f + 0.044715f*v*v);
              const float e = __builtin_amdgcn_exp2f(u * 2.885390082f);
              vv[r] = 0.5f*v*(1.0f + (1.0f - 2.0f/(1.0f + e)));
            }
            uint2 pkd = make_uint2(pk2(vv[0], vv[1]), pk2(vv[2], vv[3]));
            *(uint2*)((unsigned short*)out0 + (size_t)tok*4096 + row0) = pkd;
          } else if (MODE == 4){
            uint2 pkd = make_uint2(pk2(v0, v1), pk2(v2, v3));
            unsigned short* o = (unsigned short*)(kz ? out1 : out0);
            *(uint2*)(o + (size_t)tok*1024 + row0) = pkd;
          } else { // MODE 3: QKV split, Q scaled
            if (row0 < 1024){
              const float s = 0.18033688011112042f;
              uint2 pkd = make_uint2(pk2(v0*s, v1*s), pk2(v2*s, v3*s));
              *(uint2*)((unsigned short*)out0 + (size_t)tok*1024 + row0) = pkd;
            } else if (row0 < 2048){
              uint2 pkd = make_uint2(pk2(v0, v1), pk2(v2, v3));
              *(uint2*)((unsigned short*)out1 + (size_t)tok*1024 + (row0-1024)) = pkd;
            } else {
              uint2 pkd = make_uint2(pk2(v0, v1), pk2(v2, v3));
              *(uint2*)((unsigned short*)out2 + (size_t)tok*1024 + (row0-2048)) = pkd;
            }
          }
        }
      }
    }
  }
}

// ---------------- Vtok [b,s][h*64+f] -> Vt [bh][f][s] transpose ----------------
__global__ __launch_bounds__(256) void vtrans(const unsigned short* __restrict__ Vtok,
                                              unsigned short* __restrict__ Vt){
  __shared__ unsigned short tile[64][65];
  const int st = blockIdx.x, bh = blockIdx.y;
  const int b = bh >> 4, h = bh & 15;
  const int t = threadIdx.x;
  {
    const int r = t >> 2, cc = (t & 3) * 16;
    const unsigned short* src = Vtok + (size_t)((b<<11) + (st<<6) + r)*1024 + (h<<6) + cc;
    ushort8 u0 = *(const ushort8*)src;
    ushort8 u1 = *(const ushort8*)(src + 8);
    #pragma unroll
    for (int j=0;j<8;j++){ tile[r][cc+j] = u0[j]; tile[r][cc+8+j] = u1[j]; }
  }
  __syncthreads();
  const int f = t >> 2, ss = (t & 3) * 16;
  ushort8 w0, w1;
  #pragma unroll
  for (int j=0;j<8;j++){ w0[j] = tile[ss+j][f]; w1[j] = tile[ss+8+j][f]; }
  unsigned short* dst = Vt + (size_t)bh*64*2048 + (size_t)f*2048 + (st<<6) + ss;
  *(ushort8*)dst = w0;
  *(ushort8*)(dst + 8) = w1;
}

// ---------------- causal flash attention, fused pairs, FIXED-MAX softmax ----------------
// (256,4): 4 blocks/CU, all 1024 blocks co-resident (no tail round).
// T14 async-STAGE split: K/V(kt+1) loaded to REGISTERS before compute(kt)
// (HBM/L2 latency hides under QK+softmax+PV), then barrier -> ds_write ->
// barrier. Replaces gl_lds+sync which exposed the DMA drain every iteration.
// Same per-lane source addresses and LDS layout -> bitwise-identical.
__global__ __launch_bounds__(256, 4) void attn(const unsigned short* __restrict__ Q,
                                               const unsigned short* __restrict__ Kg,
                                               const unsigned short* __restrict__ Vt,
                                               unsigned short* __restrict__ O){
  __shared__ __align__(16) unsigned short Ks[64*64];
  __shared__ __align__(16) unsigned short Vs[64*64];
  __shared__ __align__(16) unsigned short PT[4][2][16*68];

  const int lin = blockIdx.x;
  const int bh = lin & 63;
  const int qt_lo = lin >> 6;          // 0..15
  const int qt_hi = 31 - qt_lo;        // 16..31
  const int b = bh >> 4, h = bh & 15;
  const int tid = threadIdx.x, wave = tid >> 6, lane = tid & 63;
  const int quad = lane >> 4, l15 = lane & 15;
  const float FM = 12.0f;              // fixed softmax max (log2 units)

  const size_t qbase = (size_t)((b<<11) + (wave<<4) + l15)*1024 + (h<<6);
  bf16x8 qf_hi[2], qf_lo[2];
  qf_hi[0] = *(const bf16x8*)(Q + qbase + (size_t)(qt_hi<<6)*1024 + quad*8);
  qf_hi[1] = *(const bf16x8*)(Q + qbase + (size_t)(qt_hi<<6)*1024 + 32 + quad*8);
  qf_lo[0] = *(const bf16x8*)(Q + qbase + (size_t)(qt_lo<<6)*1024 + quad*8);
  qf_lo[1] = *(const bf16x8*)(Q + qbase + (size_t)(qt_lo<<6)*1024 + 32 + quad*8);

  floatx4 oa_hi[4], oa_lo[4];
  #pragma unroll
  for (int i=0;i<4;i++){ oa_hi[i] = (floatx4)0.0f; oa_lo[i] = (floatx4)0.0f; }
  float li_hi = 0.0f, li_lo = 0.0f;

  const unsigned short* Kbh = Kg + ((size_t)(b<<11))*1024 + (h<<6);
  const unsigned short* Vbh = Vt + (size_t)bh*64*2048;
  unsigned short* Pw0 = &PT[wave][0][0];
  unsigned short* Pw1 = &PT[wave][1][0];

  const int slot0 = wave*128 + lane;
  const int krow0 = slot0 >> 3, kc0 = (slot0 & 7) ^ (krow0 & 7);
  const int slot1 = slot0 + 64;
  const int krow1 = slot1 >> 3, kc1 = (slot1 & 7) ^ (krow1 & 7);

  // T14 reg-staging buffers (+16 VGPR)
  ushort8 kr0, kr1, vr0, vr1;
  auto load_kv = [&](int kt){
    kr0 = *(const ushort8*)(Kbh + (size_t)((kt<<6) + krow0)*1024 + kc0*8);
    kr1 = *(const ushort8*)(Kbh + (size_t)((kt<<6) + krow1)*1024 + kc1*8);
    vr0 = *(const ushort8*)(Vbh + (size_t)krow0*2048 + (kt<<6) + kc0*8);
    vr1 = *(const ushort8*)(Vbh + (size_t)krow1*2048 + (kt<<6) + kc1*8);
  };
  auto write_kv = [&](){
    *(ushort8*)(Ks + wave*1024 + lane*8)       = kr0;
    *(ushort8*)(Ks + wave*1024 + 512 + lane*8) = kr1;
    *(ushort8*)(Vs + wave*1024 + lane*8)       = vr0;
    *(ushort8*)(Vs + wave*1024 + 512 + lane*8) = vr1;
  };

  auto softmax_P = [&](floatx4* sa, float& li, unsigned short* Pbuf, bool diag){
    if (diag){
      const int qrow = (wave<<4) + l15;
      #pragma unroll
      for (int tj=0;tj<4;tj++)
        #pragma unroll
        for (int r=0;r<4;r++)
          if (tj*16 + quad*4 + r > qrow) sa[tj][r] = -1e30f;
    }
    float rs = 0.0f;
    #pragma unroll
    for (int tj=0;tj<4;tj++)
      #pragma unroll
      for (int r=0;r<4;r++){
        const float p = __builtin_amdgcn_exp2f(sa[tj][r] - FM);
        sa[tj][r] = p;
        rs += p;
      }
    li += rs;
    #pragma unroll
    for (int tj=0;tj<4;tj++){
      uint2 pkd = make_uint2(pk2(sa[tj][0], sa[tj][1]), pk2(sa[tj][2], sa[tj][3]));
      *(uint2*)(Pbuf + l15*68 + tj*16 + quad*4) = pkd;
    }
  };

  // prologue: stage kt=0
  load_kv(0); write_kv();
  __syncthreads();

  for (int kt = 0; kt <= qt_hi; ++kt){
    if (kt < qt_hi) load_kv(kt+1);     // prefetch next tile into regs

    if (kt <= qt_lo){
      floatx4 sh[4], sl[4];
      __builtin_amdgcn_s_setprio(1);
      #pragma unroll
      for (int tj=0;tj<4;tj++){
        sh[tj] = (floatx4)0.0f; sl[tj] = (floatx4)0.0f;
        #pragma unroll
        for (int ks=0;ks<2;ks++){
          const int n = tj*16 + l15;
          const int c = (ks*4 + quad) ^ (n & 7);
          const bf16x8 kf = *(const bf16x8*)(Ks + n*64 + c*8);
          sh[tj] = __builtin_amdgcn_mfma_f32_16x16x32_bf16(kf, qf_hi[ks], sh[tj], 0,0,0);
          sl[tj] = __builtin_amdgcn_mfma_f32_16x16x32_bf16(kf, qf_lo[ks], sl[tj], 0,0,0);
        }
      }
      __builtin_amdgcn_s_setprio(0);
      softmax_P(sh, li_hi, Pw0, false);
      softmax_P(sl, li_lo, Pw1, kt == qt_lo);
      __builtin_amdgcn_s_setprio(1);
      #pragma unroll
      for (int ks2=0;ks2<2;ks2++){
        const bf16x8 pfh = *(const bf16x8*)(Pw0 + l15*68 + ks2*32 + quad*8);
        const bf16x8 pfl = *(const bf16x8*)(Pw1 + l15*68 + ks2*32 + quad*8);
        #pragma unroll
        for (int tn=0;tn<4;tn++){
          const int n2 = tn*16 + l15;
          const int c = (ks2*4 + quad) ^ (n2 & 7);
          const bf16x8 vf = *(const bf16x8*)(Vs + n2*64 + c*8);
          oa_hi[tn] = __builtin_amdgcn_mfma_f32_16x16x32_bf16(vf, pfh, oa_hi[tn], 0,0,0);
          oa_lo[tn] = __builtin_amdgcn_mfma_f32_16x16x32_bf16(vf, pfl, oa_lo[tn], 0,0,0);
        }
      }
      __builtin_amdgcn_s_setprio(0);
    } else {
      floatx4 sh[4];
      __builtin_amdgcn_s_setprio(1);
      #pragma unroll
      for (int tj=0;tj<4;tj++){
        sh[tj] = (floatx4)0.0f;
        #pragma unroll
        for (int ks=0;ks<2;ks++){
          const int n = tj*16 + l15;
          const int c = (ks*4 + quad) ^ (n & 7);
          const bf16x8 kf = *(const bf16x8*)(Ks + n*64 + c*8);
          sh[tj] = __builtin_amdgcn_mfma_f32_16x16x32_bf16(kf, qf_hi[ks], sh[tj], 0,0,0);
        }
      }
      __builtin_amdgcn_s_setprio(0);
      softmax_P(sh, li_hi, Pw0, kt == qt_hi);
      __builtin_amdgcn_s_setprio(1);
      #pragma unroll
      for (int ks2=0;ks2<2;ks2++){
        const bf16x8 pfh = *(const bf16x8*)(Pw0 + l15*68 + ks2*32 + quad*8);
        #pragma unroll
        for (int tn=0;tn<4;tn++){
          const int n2 = tn*16 + l15;
          const int c = (ks2*4 + quad) ^ (n2 & 7);
          const bf16x8 vf = *(const bf16x8*)(Vs + n2*64 + c*8);
          oa_hi[tn] = __builtin_amdgcn_mfma_f32_16x16x32_bf16(vf, pfh, oa_hi[tn], 0,0,0);
        }
      }
      __builtin_amdgcn_s_setprio(0);
    }

    __syncthreads();                    // all waves done reading LDS(kt)
    if (kt < qt_hi) write_kv();         // land kt+1 (compiler inserts vmcnt)
    __syncthreads();                    // kt+1 visible
  }

  li_hi += __shfl_xor(li_hi, 16, 64);
  li_hi += __shfl_xor(li_hi, 32, 64);
  li_lo += __shfl_xor(li_lo, 16, 64);
  li_lo += __shfl_xor(li_lo, 32, 64);
  {
    const float inv = 1.0f / li_hi;
    unsigned short* Orow = O + (size_t)((b<<11) + (qt_hi<<6) + (wave<<4) + l15)*1024 + (h<<6);
    #pragma unroll
    for (int tn=0;tn<4;tn++){
      uint2 pkd = make_uint2(pk2(oa_hi[tn][0]*inv, oa_hi[tn][1]*inv),
                             pk2(oa_hi[tn][2]*inv, oa_hi[tn][3]*inv));
      *(uint2*)(Orow + tn*16 + quad*4) = pkd;
    }
  }
  {
    const float inv = 1.0f / li_lo;
    unsigned short* Orow = O + (size_t)((b<<11) + (qt_lo<<6) + (wave<<4) + l15)*1024 + (h<<6);
    #pragma unroll
    for (int tn=0;tn<4;tn++){
      uint2 pkd = make_uint2(pk2(oa_lo[tn][0]*inv, oa_lo[tn][1]*inv),
                             pk2(oa_lo[tn][2]*inv, oa_lo[tn][3]*inv));
      *(uint2*)(Orow + tn*16 + quad*4) = pkd;
    }
  }
}

// ---------------- residual + LayerNorm (fp32 second source) ----------------
__global__ __launch_bounds__(256) void ln_res(const float* __restrict__ a,
                                              const float* __restrict__ bsrc,
                                              const float* __restrict__ g,
                                              const float* __restrict__ be,
                                              float* __restrict__ of,
                                              unsigned short* __restrict__ ob){
  __shared__ float red1[4], red2[4];
  const int row = blockIdx.x, t = threadIdx.x;
  const int wave = t >> 6, lane = t & 63;
  const float4 va = *(const float4*)(a + (size_t)row*1024 + t*4);
  const float4 vb = *(const float4*)(bsrc + (size_t)row*1024 + t*4);
  float xs[4] = {va.x+vb.x, va.y+vb.y, va.z+vb.z, va.w+vb.w};
  float s = xs[0]+xs[1]+xs[2]+xs[3];
  #pragma unroll
  for (int d=1; d<64; d<<=1) s += __shfl_xor(s, d, 64);
  if (lane==0) red1[wave] = s;
  __syncthreads();
  const float mean = (red1[0]+red1[1]+red1[2]+red1[3]) * (1.0f/1024.0f);
  float vsum = 0.0f;
  #pragma unroll
  for (int i=0;i<4;i++){ const float d = xs[i]-mean; vsum += d*d; }
  #pragma unroll
  for (int d=1; d<64; d<<=1) vsum += __shfl_xor(vsum, d, 64);
  if (lane==0) red2[wave] = vsum;
  __syncthreads();
  const float var = (red2[0]+red2[1]+red2[2]+red2[3]) * (1.0f/1024.0f);
  const float rs = rsqrtf(var + 1e-5f);
  const float4 gg = *(const float4*)(g + t*4);
  const float4 bb = *(const float4*)(be + t*4);
  float y[4];
  y[0] = (xs[0]-mean)*rs*gg.x + bb.x;
  y[1] = (xs[1]-mean)*rs*gg.y + bb.y;
  y[2] = (xs[2]-mean)*rs*gg.z + bb.z;
  y[3] = (xs[3]-mean)*rs*gg.w + bb.w;
  if (of){
    float4 o4; o4.x=y[0]; o4.y=y[1]; o4.z=y[2]; o4.w=y[3];
    *(float4*)(of + (size_t)row*1024 + t*4) = o4;
  }
  if (ob){
    ushort4v u = { f2bs(y[0]), f2bs(y[1]), f2bs(y[2]), f2bs(y[3]) };
    *(ushort4v*)(ob + (size_t)row*1024 + t*4) = u;
  }
}

// ---------------- residual + LayerNorm (two bf16 partial sources) ----------------
__global__ __launch_bounds__(256) void ln_res2(const float* __restrict__ a,
                                               const unsigned short* __restrict__ p0,
                                               const unsigned short* __restrict__ p1,
                                               const float* __restrict__ g,
                                               const float* __restrict__ be,
                                               float* __restrict__ of){
  __shared__ float red1[4], red2[4];
  const int row = blockIdx.x, t = threadIdx.x;
  const int wave = t >> 6, lane = t & 63;
  const float4 va = *(const float4*)(a + (size_t)row*1024 + t*4);
  const ushort4v u0 = *(const ushort4v*)(p0 + (size_t)row*1024 + t*4);
  const ushort4v u1 = *(const ushort4v*)(p1 + (size_t)row*1024 + t*4);
  float xs[4] = { va.x + bs2f(u0[0]) + bs2f(u1[0]),
                  va.y + bs2f(u0[1]) + bs2f(u1[1]),
                  va.z + bs2f(u0[2]) + bs2f(u1[2]),
                  va.w + bs2f(u0[3]) + bs2f(u1[3]) };
  float s = xs[0]+xs[1]+xs[2]+xs[3];
  #pragma unroll
  for (int d=1; d<64; d<<=1) s += __shfl_xor(s, d, 64);
  if (lane==0) red1[wave] = s;
  __syncthreads();
  const float mean = (red1[0]+red1[1]+red1[2]+red1[3]) * (1.0f/1024.0f);
  float vsum = 0.0f;
  #pragma unroll
  for (int i=0;i<4;i++){ const float d = xs[i]-mean; vsum += d*d; }
  #pragma unroll
  for (int d=1; d<64; d<<=1) vsum += __shfl_xor(vsum, d, 64);
  if (lane==0) red2[wave] = vsum;
  __syncthreads();
  const float var = (red2[0]+red2[1]+red2[2]+red2[3]) * (1.0f/1024.0f);
  const float rs = rsqrtf(var + 1e-5f);
  const float4 gg = *(const float4*)(g + t*4);
  const float4 bb = *(const float4*)(be + t*4);
  float4 o4;
  o4.x = (xs[0]-mean)*rs*gg.x + bb.x;
  o4.y = (xs[1]-mean)*rs*gg.y + bb.y;
  o4.z = (xs[2]-mean)*rs*gg.z + bb.z;
  o4.w = (xs[3]-mean)*rs*gg.w + bb.w;
  *(float4*)(of + (size_t)row*1024 + t*4) = o4;
}

extern "C" void kernel_launch(void* const* d_in, const int* in_sizes, int n_in,
                              void* d_out, int out_size, void* d_ws, size_t ws_size,
                              hipStream_t stream){
  (void)in_sizes; (void)n_in; (void)out_size; (void)ws_size;
  const float* x  = (const float*)d_in[0];
  const float* wq = (const float*)d_in[1];
  const float* bq = (const float*)d_in[2];
  const float* wk = (const float*)d_in[3];
  const float* bk = (const float*)d_in[4];
  const float* wv = (const float*)d_in[5];
  const float* bv = (const float*)d_in[6];
  const float* wo = (const float*)d_in[7];
  const float* bo = (const float*)d_in[8];
  const float* w1 = (const float*)d_in[9];
  const float* b1 = (const float*)d_in[10];
  const float* w2 = (const float*)d_in[11];
  const float* b2 = (const float*)d_in[12];
  const float* g1 = (const float*)d_in[13];
  const float* be1= (const float*)d_in[14];
  const float* g2 = (const float*)d_in[15];
  const float* be2= (const float*)d_in[16];
  float* out = (float*)d_out;

  char* ws = (char*)d_ws;
  size_t off = 0;
  auto take = [&](size_t bytes)->char*{
    char* p = ws + off; off += (bytes + 255) & ~(size_t)255; return p;
  };
  unsigned short* Xb  = (unsigned short*)take(8192UL*1024*2);
  unsigned short* Qb  = (unsigned short*)take(8192UL*1024*2);
  unsigned short* Kb  = (unsigned short*)take(8192UL*1024*2);
  unsigned short* Vtb = (unsigned short*)take(8192UL*1024*2);
  unsigned short* Ob  = (unsigned short*)take(8192UL*1024*2);
  unsigned short* Midb= Qb;                    // alias: spans Qb..Ob (64 MB), dead by FFN1
  unsigned short* Vtok= (unsigned short*)take(8192UL*1024*2);
  unsigned short* Wqkv= (unsigned short*)take(3072UL*1024*2);
  float*          Bqkv= (float*)take(3072UL*4);
  unsigned short* Wot = (unsigned short*)take(1024UL*1024*2);
  unsigned short* W1t = (unsigned short*)take(4096UL*1024*2);
  unsigned short* W2t = (unsigned short*)take(1024UL*4096*2);
  float*          C1  = (float*)take(8192UL*1024*4);
  unsigned short* F0  = (unsigned short*)C1;   // alias: C1 dead after LN1; F0+F1 = 32 MB
  unsigned short* F1  = F0 + 8192UL*1024;
  float*          Hf  = (float*)take(8192UL*1024*4);
  unsigned short* Hb  = (unsigned short*)take(8192UL*1024*2);

  // 1. fused prep: cvt_x + pack_qkv + 3x transpose_pack (one launch)
  prep<<<14336, 256, 0, stream>>>(x, Xb, wq, wk, wv, bq, bk, bv,
                                  Wqkv, Bqkv, wo, Wot, w1, W1t, w2, W2t);

  // 2. fused QKV projection (PIPE=1 counted schedule) + V transpose
  gemm256<3,1><<<12*32, 512, 0, stream>>>(Wqkv, Xb, Bqkv, Qb, Kb, Vtok, 1024, 1024);
  vtrans<<<dim3(32,64), 256, 0, stream>>>(Vtok, Vtb);

  // 3. causal flash attention (T14 reg-prefetch, fixed-max softmax, 4 blocks/CU)
  attn<<<1024, 256, 0, stream>>>(Qb, Kb, Vtb, Ob);

  // 4. output projection (fp32, 128^2 kernel) -> residual + LN1
  gemm_tn<1><<<8*64, 256, 0, stream>>>(Wot, Ob, bo, C1, nullptr, nullptr, 1024, 1024, 1024);
  ln_res<<<8192, 256, 0, stream>>>(x, C1, g1, be1, Hf, Hb);

  // 5. FFN: gelu(h@w1+b1) -> Midb (PIPE=0); w2 split-K x2 -> bf16 partials (PIPE=1)
  gemm256<2,0><<<16*32, 512, 0, stream>>>(W1t, Hb, b1, Midb, nullptr, nullptr, 1024, 1024);
  gemm256<4,1><<<dim3(4*32,1,2), 512, 0, stream>>>(W2t, Midb, b2, F0, F1, nullptr, 4096, 2048);
  ln_res2<<<8192, 256, 0, stream>>>(Hf, F0, F1, g2, be2, out);
}

// Round 7
// 502.451 us; speedup vs baseline: 1.1182x; 1.1182x over previous
//
#include <hip/hip_runtime.h>
#include <hip/hip_bf16.h>
#include <math.h>

typedef __bf16 bf16x8 __attribute__((ext_vector_type(8)));
typedef float floatx4 __attribute__((ext_vector_type(4)));
typedef unsigned short ushort8 __attribute__((ext_vector_type(8)));
typedef unsigned short ushort4v __attribute__((ext_vector_type(4)));

__device__ __forceinline__ unsigned short f2bs(float f){
  union { float f; unsigned u; } v; v.f = f;
  unsigned r = v.u + 0x7fffu + ((v.u >> 16) & 1u);
  return (unsigned short)(r >> 16);
}
__device__ __forceinline__ float bs2f(unsigned short s){
  union { unsigned u; float f; } v; v.u = ((unsigned)s) << 16; return v.f;
}
// packed f32x2 -> bf16x2 (RNE)
__device__ __forceinline__ unsigned pk2(float a, float b){
  union { __hip_bfloat162 h; unsigned u; } cv;
  cv.h = __float22bfloat162_rn(make_float2(a, b));
  return cv.u;
}
__device__ __forceinline__ void gl_lds16(const void* g, void* l){
  __builtin_amdgcn_global_load_lds(
      (const __attribute__((address_space(1))) void*)g,
      (__attribute__((address_space(3))) void*)l,
      16, 0, 0);
}

// ---------------- fused prep: cvt_x + pack_qkv + 3x transpose_pack ----------------
// One launch instead of five. Flat 1D grid, whole blocks per path:
//   [0,8192):      x fp32 -> Xb bf16
//   [8192,9728):   pack wq/wk/wv -> Wqkv_t [3072][1024] + bias
//   [9728,10240):  wo  [1024][1024] -> Wot  (bf16 [C][R])
//   [10240,12288): w1  [1024][4096] -> W1t
//   [12288,14336): w2  [4096][1024] -> W2t
__global__ __launch_bounds__(256) void prep(
    const float* __restrict__ x,  unsigned short* __restrict__ Xb,
    const float* __restrict__ wq, const float* __restrict__ wk,
    const float* __restrict__ wv, const float* __restrict__ bq,
    const float* __restrict__ bk, const float* __restrict__ bv,
    unsigned short* __restrict__ Wqkv, float* __restrict__ Bqkv,
    const float* __restrict__ wo, unsigned short* __restrict__ Wot,
    const float* __restrict__ w1, unsigned short* __restrict__ W1t,
    const float* __restrict__ w2, unsigned short* __restrict__ W2t){
  __shared__ float tile[32][65];
  const int blk = blockIdx.x, t = threadIdx.x;

  if (blk < 8192){                       // ---- cvt_x ----
    const int i = (blk*256 + t)*4;
    const float4 v = *(const float4*)(x + i);
    ushort4v u = { f2bs(v.x), f2bs(v.y), f2bs(v.z), f2bs(v.w) };
    *(ushort4v*)(Xb + i) = u;
    return;
  }

  if (blk < 9728){                       // ---- pack_qkv ----
    const int p = blk - 8192;
    const int dt = p & 31, h = (p>>5)&15, sel = p>>9;
    const float* src = (sel==0 ? wq : (sel==1 ? wk : wv)) + (size_t)h*65536;
    const int d0 = dt*32;
    {
      const int r = t >> 3, cc = (t & 7)*8;
      const float* pp = src + (size_t)(d0+r)*64 + cc;
      const float4 v0 = *(const float4*)pp;
      const float4 v1 = *(const float4*)(pp+4);
      tile[r][cc+0]=v0.x; tile[r][cc+1]=v0.y; tile[r][cc+2]=v0.z; tile[r][cc+3]=v0.w;
      tile[r][cc+4]=v1.x; tile[r][cc+5]=v1.y; tile[r][cc+6]=v1.z; tile[r][cc+7]=v1.w;
    }
    __syncthreads();
    const int f = t >> 2, rr = (t & 3)*8;
    ushort8 u;
    #pragma unroll
    for (int j=0;j<8;j++) u[j] = f2bs(tile[rr+j][f]);
    const size_t n = (size_t)sel*1024 + h*64 + f;
    *(ushort8*)(Wqkv + n*1024 + d0 + rr) = u;
    if (dt==0 && t<64){
      const float* bs = (sel==0 ? bq : (sel==1 ? bk : bv)) + h*64;
      Bqkv[sel*1024 + h*64 + t] = bs[t];
    }
    return;
  }

  // ---- transpose_pack (3 matrices) ----
  const float* src; unsigned short* dst; int R, C, bx, by;
  if (blk < 10240){ const int q = blk-9728;  src=wo; dst=Wot; R=1024; C=1024; bx=q&15; by=q>>4; }
  else if (blk < 12288){ const int q = blk-10240; src=w1; dst=W1t; R=1024; C=4096; bx=q&63; by=q>>6; }
  else { const int q = blk-12288; src=w2; dst=W2t; R=4096; C=1024; bx=q&15; by=q>>4; }
  const int r0 = by*32, c0 = bx*64;
  {
    const int r = t >> 3, cc = (t & 7)*8;
    const float* p = src + (size_t)(r0+r)*C + c0 + cc;
    const float4 v0 = *(const float4*)p;
    const float4 v1 = *(const float4*)(p+4);
    tile[r][cc+0]=v0.x; tile[r][cc+1]=v0.y; tile[r][cc+2]=v0.z; tile[r][cc+3]=v0.w;
    tile[r][cc+4]=v1.x; tile[r][cc+5]=v1.y; tile[r][cc+6]=v1.z; tile[r][cc+7]=v1.w;
  }
  __syncthreads();
  const int f = t >> 2, rr = (t & 3)*8;
  ushort8 u;
  #pragma unroll
  for (int j=0;j<8;j++) u[j] = f2bs(tile[rr+j][f]);
  *(ushort8*)(dst + (size_t)(c0+f)*R + r0 + rr) = u;
}

// ---------------- transposed-orientation bf16 GEMM (128^2, kept for Wo) ----------------
template<int MODE>
__global__ __launch_bounds__(256, 4)
void gemm_tn(const unsigned short* __restrict__ A,
             const unsigned short* __restrict__ Bt,
             const float* __restrict__ bias,
             void* __restrict__ out0,
             void* __restrict__ out1,
             void* __restrict__ out2,
             int K, int OW, int klen){
  __shared__ __align__(16) unsigned short As[128*32];
  __shared__ __align__(16) unsigned short Bs[128*32];
  const int tid = threadIdx.x;
  const int wave = tid >> 6, lane = tid & 63;
  const int quad = lane >> 4, l15 = lane & 15;
  const int lin = blockIdx.x;
  const int n0 = (lin & 63) << 7;
  const int m0 = (lin >> 6) << 7;
  const int kz = blockIdx.z;
  const int kbase = kz * klen;
  const int wr = (wave >> 1) << 6, wc = (wave & 1) << 6;

  floatx4 acc[4][4];
  #pragma unroll
  for (int i=0;i<4;i++)
    #pragma unroll
    for (int j=0;j<4;j++) acc[i][j] = (floatx4)0.0f;

  const unsigned short* gA[2];
  const unsigned short* gB[2];
  int lofs[2];
  #pragma unroll
  for (int r2=0;r2<2;r2++){
    const int slot = r2*256 + tid;
    const int rp = slot >> 3, rem = slot & 7;
    const int row = rp*2 + (rem >> 2);
    const int kc = (rem & 3) ^ (rp & 3);
    gA[r2] = A  + (size_t)(m0 + row)*K + kbase + kc*8;
    gB[r2] = Bt + (size_t)(n0 + row)*K + kbase + kc*8;
    lofs[r2] = slot*8;
  }
  int aofs[4], bofs[4];
  #pragma unroll
  for (int t=0;t<4;t++){
    const int ra = wr + t*16 + l15;
    aofs[t] = (ra>>1)*64 + (ra&1)*32 + ((quad ^ ((ra>>1)&3))<<3);
    const int rb = wc + t*16 + l15;
    bofs[t] = (rb>>1)*64 + (rb&1)*32 + ((quad ^ ((rb>>1)&3))<<3);
  }

  for (int k0 = 0; k0 < klen; k0 += 32){
    gl_lds16(gA[0] + k0, As + lofs[0]);
    gl_lds16(gA[1] + k0, As + lofs[1]);
    gl_lds16(gB[0] + k0, Bs + lofs[0]);
    gl_lds16(gB[1] + k0, Bs + lofs[1]);
    __syncthreads();
    bf16x8 af[4];
    #pragma unroll
    for (int t=0;t<4;t++) af[t] = *(const bf16x8*)(&As[aofs[t]]);
    #pragma unroll
    for (int j=0;j<4;j++){
      const bf16x8 bv = *(const bf16x8*)(&Bs[bofs[j]]);
      #pragma unroll
      for (int i=0;i<4;i++)
        acc[i][j] = __builtin_amdgcn_mfma_f32_16x16x32_bf16(af[i], bv, acc[i][j], 0,0,0);
    }
    __syncthreads();
  }

  #pragma unroll
  for (int i=0;i<4;i++){
    const int row0 = m0 + wr + i*16 + quad*4;
    float4 b4 = make_float4(0.f,0.f,0.f,0.f);
    if (MODE != 4 || kz == 0) b4 = *(const float4*)(bias + row0);
    #pragma unroll
    for (int j=0;j<4;j++){
      const int tok = n0 + wc + j*16 + l15;
      float v0 = acc[i][j][0] + b4.x;
      float v1 = acc[i][j][1] + b4.y;
      float v2 = acc[i][j][2] + b4.z;
      float v3 = acc[i][j][3] + b4.w;
      if (MODE == 1){
        float4 o4; o4.x=v0; o4.y=v1; o4.z=v2; o4.w=v3;
        *(float4*)((float*)out0 + (size_t)tok*OW + row0) = o4;
      } else if (MODE == 2){
        float vv[4] = {v0,v1,v2,v3};
        #pragma unroll
        for (int r=0;r<4;r++){
          const float v = vv[r];
          const float u = 0.7978845608f*v*(1.0f + 0.044715f*v*v);
          const float e = __builtin_amdgcn_exp2f(u * 2.885390082f);
          vv[r] = 0.5f*v*(1.0f + (1.0f - 2.0f/(1.0f + e)));
        }
        uint2 pkd = make_uint2(pk2(vv[0], vv[1]), pk2(vv[2], vv[3]));
        *(uint2*)((unsigned short*)out0 + (size_t)tok*4096 + row0) = pkd;
      } else if (MODE == 4){
        uint2 pkd = make_uint2(pk2(v0, v1), pk2(v2, v3));
        unsigned short* o = (unsigned short*)(kz ? out1 : out0);
        *(uint2*)(o + (size_t)tok*1024 + row0) = pkd;
      } else {
        if (row0 < 1024){
          const float s = 0.18033688011112042f;
          uint2 pkd = make_uint2(pk2(v0*s, v1*s), pk2(v2*s, v3*s));
          *(uint2*)((unsigned short*)out0 + (size_t)tok*1024 + row0) = pkd;
        } else if (row0 < 2048){
          uint2 pkd = make_uint2(pk2(v0, v1), pk2(v2, v3));
          *(uint2*)((unsigned short*)out1 + (size_t)tok*1024 + (row0-1024)) = pkd;
        } else {
          uint2 pkd = make_uint2(pk2(v0, v1), pk2(v2, v3));
          *(uint2*)((unsigned short*)out2 + (size_t)tok*1024 + (row0-2048)) = pkd;
        }
      }
    }
  }
}

// ---------------- 256x256 pipelined bf16 GEMM, per-instance schedule ----------------
// PIPE=0 (measured best for FFN1, 96-99us in R3/R5): barrier+lgkmcnt(0)/phase.
// PIPE=1 (measured best for QKV/FFN2, R4): counted lgkm, 2 barriers/tile.
#define VMCNT4 asm volatile("s_waitcnt vmcnt(4)" ::: "memory")
#define VMCNT0 asm volatile("s_waitcnt vmcnt(0)" ::: "memory")
#define TAILW { if (tg < NT-2) VMCNT4; else VMCNT0; }
#define LGKM4 { asm volatile("s_waitcnt lgkmcnt(4)" ::: "memory"); __builtin_amdgcn_sched_barrier(0); }
#define LGKM8 { asm volatile("s_waitcnt lgkmcnt(8)" ::: "memory"); __builtin_amdgcn_sched_barrier(0); }
#define LGKM0 { asm volatile("s_waitcnt lgkmcnt(0)" ::: "memory"); __builtin_amdgcn_sched_barrier(0); }
#define PHASE_SYNC                                                            \
    __builtin_amdgcn_s_barrier();                                             \
    asm volatile("s_waitcnt lgkmcnt(0)" ::: "memory");                        \
    __builtin_amdgcn_sched_barrier(0);

#define STAGE_A(T, H) { const int T_ = (T); if (T_ < NT){                     \
    unsigned short* l_ = lds + (T_&1)*32768 + (H)*8192;                       \
    const int ko_ = kbase + (T_<<6);                                          \
    gl_lds16(srcA##H##_0 + ko_, l_ + ch0*8);                                  \
    gl_lds16(srcA##H##_1 + ko_, l_ + ch1*8); } }
#define STAGE_B(T, H) { const int T_ = (T); if (T_ < NT){                     \
    unsigned short* l_ = lds + (T_&1)*32768 + 16384 + (H)*8192;               \
    const int ko_ = kbase + (T_<<6);                                          \
    gl_lds16(srcB##H##_0 + ko_, l_ + ch0*8);                                  \
    gl_lds16(srcB##H##_1 + ko_, l_ + ch1*8); } }

#define MFMA_Q(AF, BF, MH, NH)                                                \
    __builtin_amdgcn_s_setprio(1);                                            \
    _Pragma("unroll")                                                         \
    for (int k_=0;k_<2;k_++)                                                  \
      _Pragma("unroll")                                                       \
      for (int m_=0;m_<4;m_++)                                                \
        _Pragma("unroll")                                                     \
        for (int n_=0;n_<2;n_++)                                              \
          acc[(MH)*4+m_][(NH)*2+n_] = __builtin_amdgcn_mfma_f32_16x16x32_bf16( \
              AF[m_][k_], BF[n_][k_], acc[(MH)*4+m_][(NH)*2+n_], 0,0,0);      \
    __builtin_amdgcn_s_setprio(0);

#define RD_A(DST, BASE)                                                       \
    _Pragma("unroll")                                                         \
    for (int m_=0;m_<4;m_++)                                                  \
      _Pragma("unroll")                                                       \
      for (int k_=0;k_<2;k_++) DST[m_][k_] = *(const bf16x8*)((BASE) + aoff[m_][k_]);
#define RD_B(DST, BASE)                                                       \
    _Pragma("unroll")                                                         \
    for (int n_=0;n_<2;n_++)                                                  \
      _Pragma("unroll")                                                       \
      for (int k_=0;k_<2;k_++) DST[n_][k_] = *(const bf16x8*)((BASE) + boff[n_][k_]);

template<int MODE, int PIPE>
__global__ __launch_bounds__(512, 2)
void gemm256(const unsigned short* __restrict__ A,
             const unsigned short* __restrict__ Bt,
             const float* __restrict__ bias,
             void* __restrict__ out0,
             void* __restrict__ out1,
             void* __restrict__ out2,
             int K, int klen){
  __shared__ __align__(16) unsigned short lds[65536];   // 128 KiB
  const int tid = threadIdx.x;
  const int wave = tid >> 6, lane = tid & 63;
  const int quad = lane >> 4, l15 = lane & 15;
  const int wm = wave >> 2, wn = wave & 3;
  const int lin = blockIdx.x;
  const int n0 = (lin & 31) << 8;     // token tile (fast dim -> pins XCD)
  const int m0 = (lin >> 5) << 8;     // weight tile
  const int kz = blockIdx.z;
  const int kbase = kz * klen;
  const int NT = klen >> 6;

  const int r0 = tid >> 3;
  const int r1 = r0 + 64;
  const int g0 = (tid & 7) ^ (r0 & 7);
  const int ch0 = tid, ch1 = tid + 512;

  const unsigned short* srcA0_0 = A  + (size_t)(m0 +       r0)*K + g0*8;
  const unsigned short* srcA0_1 = A  + (size_t)(m0 +       r1)*K + g0*8;
  const unsigned short* srcA1_0 = A  + (size_t)(m0 + 128 + r0)*K + g0*8;
  const unsigned short* srcA1_1 = A  + (size_t)(m0 + 128 + r1)*K + g0*8;
  const unsigned short* srcB0_0 = Bt + (size_t)(n0 +       r0)*K + g0*8;
  const unsigned short* srcB0_1 = Bt + (size_t)(n0 +       r1)*K + g0*8;
  const unsigned short* srcB1_0 = Bt + (size_t)(n0 + 128 + r0)*K + g0*8;
  const unsigned short* srcB1_1 = Bt + (size_t)(n0 + 128 + r1)*K + g0*8;

  const int xr = l15 & 7;
  int aoff[4][2], boff[2][2];
  #pragma unroll
  for (int m=0;m<4;m++){
    const int rh = wm*64 + m*16 + l15;
    #pragma unroll
    for (int k=0;k<2;k++)
      aoff[m][k] = rh*64 + (((k*4 + quad) ^ xr) << 3);
  }
  #pragma unroll
  for (int n=0;n<2;n++){
    const int rb = wn*32 + n*16 + l15;
    #pragma unroll
    for (int k=0;k<2;k++)
      boff[n][k] = rb*64 + (((k*4 + quad) ^ xr) << 3);
  }

  floatx4 acc[8][4];
  #pragma unroll
  for (int i=0;i<8;i++)
    #pragma unroll
    for (int j=0;j<4;j++) acc[i][j] = (floatx4)0.0f;

  bf16x8 af0[4][2], af1[4][2], bf0[2][2], bf1[2][2];

  STAGE_B(0,0); STAGE_A(0,0); STAGE_A(0,1); STAGE_B(0,1);
  STAGE_B(1,0); STAGE_A(1,0);
  VMCNT4;
  __builtin_amdgcn_s_barrier();

  if (PIPE == 0){
    for (int tg = 0; tg < NT; ++tg){
      const int d = tg & 1;
      const unsigned short* A0b = lds + d*32768;
      const unsigned short* A1b = A0b + 8192;
      const unsigned short* B0b = lds + d*32768 + 16384;
      const unsigned short* B1b = B0b + 8192;

      RD_A(af0, A0b);
      RD_B(bf0, B0b);
      STAGE_A(tg+1, 1);
      PHASE_SYNC;
      MFMA_Q(af0, bf0, 0, 0);
      __builtin_amdgcn_s_barrier();

      RD_B(bf1, B1b);
      STAGE_B(tg+1, 1);
      PHASE_SYNC;
      MFMA_Q(af0, bf1, 0, 1);
      __builtin_amdgcn_s_barrier();

      RD_A(af1, A1b);
      STAGE_B(tg+2, 0);
      PHASE_SYNC;
      MFMA_Q(af1, bf1, 1, 1);
      __builtin_amdgcn_s_barrier();

      STAGE_A(tg+2, 0);
      PHASE_SYNC;
      MFMA_Q(af1, bf0, 1, 0);
      TAILW;
      __builtin_amdgcn_s_barrier();
    }
  } else {
    RD_A(af0, lds);
    RD_B(bf0, lds + 16384);

    for (int tg = 0; tg < NT; ++tg){
      const int d = tg & 1;
      const unsigned short* A1b = lds + d*32768 + 8192;
      const unsigned short* B1b = lds + d*32768 + 16384 + 8192;

      RD_B(bf1, B1b);
      STAGE_A(tg+1, 1);
      LGKM4;
      MFMA_Q(af0, bf0, 0, 0);

      RD_A(af1, A1b);
      STAGE_B(tg+1, 1);
      LGKM8;
      MFMA_Q(af0, bf1, 0, 1);
      __builtin_amdgcn_s_barrier();

      STAGE_B(tg+2, 0);
      LGKM0;
      MFMA_Q(af1, bf1, 1, 1);

      STAGE_A(tg+2, 0);
      TAILW;
      __builtin_amdgcn_s_barrier();
      {
        const unsigned short* A0n = lds + (d^1)*32768;
        const unsigned short* B0n = A0n + 16384;
        if (tg+1 < NT){ RD_A(af0, A0n); }
        MFMA_Q(af1, bf0, 1, 0);
        if (tg+1 < NT){ RD_B(bf0, B0n); }
      }
    }
  }

  // epilogue
  #pragma unroll
  for (int mh=0; mh<2; mh++){
    #pragma unroll
    for (int m=0; m<4; m++){
      const int row0 = m0 + mh*128 + wm*64 + m*16 + quad*4;
      float4 b4 = make_float4(0.f,0.f,0.f,0.f);
      if (MODE != 4 || kz == 0) b4 = *(const float4*)(bias + row0);
      #pragma unroll
      for (int nh=0; nh<2; nh++){
        #pragma unroll
        for (int n=0; n<2; n++){
          const int tok = n0 + nh*128 + wn*32 + n*16 + l15;
          const floatx4 a = acc[mh*4+m][nh*2+n];
          float v0 = a[0]+b4.x, v1 = a[1]+b4.y, v2 = a[2]+b4.z, v3 = a[3]+b4.w;
          if (MODE == 2){
            float vv[4] = {v0,v1,v2,v3};
            #pragma unroll
            for (int r=0;r<4;r++){
              const float v = vv[r];
              const float u = 0.7978845608f*v*(1.0f + 0.044715f*v*v);
              const float e = __builtin_amdgcn_exp2f(u * 2.885390082f);
              vv[r] = 0.5f*v*(1.0f + (1.0f - 2.0f/(1.0f + e)));
            }
            uint2 pkd = make_uint2(pk2(vv[0], vv[1]), pk2(vv[2], vv[3]));
            *(uint2*)((unsigned short*)out0 + (size_t)tok*4096 + row0) = pkd;
          } else if (MODE == 4){
            uint2 pkd = make_uint2(pk2(v0, v1), pk2(v2, v3));
            unsigned short* o = (unsigned short*)(kz ? out1 : out0);
            *(uint2*)(o + (size_t)tok*1024 + row0) = pkd;
          } else { // MODE 3: QKV split, Q scaled
            if (row0 < 1024){
              const float s = 0.18033688011112042f;
              uint2 pkd = make_uint2(pk2(v0*s, v1*s), pk2(v2*s, v3*s));
              *(uint2*)((unsigned short*)out0 + (size_t)tok*1024 + row0) = pkd;
            } else if (row0 < 2048){
              uint2 pkd = make_uint2(pk2(v0, v1), pk2(v2, v3));
              *(uint2*)((unsigned short*)out1 + (size_t)tok*1024 + (row0-1024)) = pkd;
            } else {
              uint2 pkd = make_uint2(pk2(v0, v1), pk2(v2, v3));
              *(uint2*)((unsigned short*)out2 + (size_t)tok*1024 + (row0-2048)) = pkd;
            }
          }
        }
      }
    }
  }
}

// ---------------- Vtok [b,s][h*64+f] -> Vt [bh][f][s] transpose ----------------
__global__ __launch_bounds__(256) void vtrans(const unsigned short* __restrict__ Vtok,
                                              unsigned short* __restrict__ Vt){
  __shared__ unsigned short tile[64][65];
  const int st = blockIdx.x, bh = blockIdx.y;
  const int b = bh >> 4, h = bh & 15;
  const int t = threadIdx.x;
  {
    const int r = t >> 2, cc = (t & 3) * 16;
    const unsigned short* src = Vtok + (size_t)((b<<11) + (st<<6) + r)*1024 + (h<<6) + cc;
    ushort8 u0 = *(const ushort8*)src;
    ushort8 u1 = *(const ushort8*)(src + 8);
    #pragma unroll
    for (int j=0;j<8;j++){ tile[r][cc+j] = u0[j]; tile[r][cc+8+j] = u1[j]; }
  }
  __syncthreads();
  const int f = t >> 2, ss = (t & 3) * 16;
  ushort8 w0, w1;
  #pragma unroll
  for (int j=0;j<8;j++){ w0[j] = tile[ss+j][f]; w1[j] = tile[ss+8+j][f]; }
  unsigned short* dst = Vt + (size_t)bh*64*2048 + (size_t)f*2048 + (st<<6) + ss;
  *(ushort8*)dst = w0;
  *(ushort8*)(dst + 8) = w1;
}

// ---------------- causal flash attention, fused pairs, FIXED-MAX softmax ----------------
// REVERTED to gl_lds staging (R4/R5 version — T14 reg-staging regressed in R6;
// gl_lds wins when linear LDS layout works, per m151). (256,4): 4 blocks/CU,
// all 1024 blocks co-resident in one round; setprio around MFMA clusters.
__global__ __launch_bounds__(256, 4) void attn(const unsigned short* __restrict__ Q,
                                               const unsigned short* __restrict__ Kg,
                                               const unsigned short* __restrict__ Vt,
                                               unsigned short* __restrict__ O){
  __shared__ __align__(16) unsigned short Ks[64*64];
  __shared__ __align__(16) unsigned short Vs[64*64];
  __shared__ __align__(16) unsigned short PT[4][2][16*68];

  const int lin = blockIdx.x;
  const int bh = lin & 63;
  const int qt_lo = lin >> 6;          // 0..15
  const int qt_hi = 31 - qt_lo;        // 16..31
  const int b = bh >> 4, h = bh & 15;
  const int tid = threadIdx.x, wave = tid >> 6, lane = tid & 63;
  const int quad = lane >> 4, l15 = lane & 15;
  const float FM = 12.0f;              // fixed softmax max (log2 units)

  const size_t qbase = (size_t)((b<<11) + (wave<<4) + l15)*1024 + (h<<6);
  bf16x8 qf_hi[2], qf_lo[2];
  qf_hi[0] = *(const bf16x8*)(Q + qbase + (size_t)(qt_hi<<6)*1024 + quad*8);
  qf_hi[1] = *(const bf16x8*)(Q + qbase + (size_t)(qt_hi<<6)*1024 + 32 + quad*8);
  qf_lo[0] = *(const bf16x8*)(Q + qbase + (size_t)(qt_lo<<6)*1024 + quad*8);
  qf_lo[1] = *(const bf16x8*)(Q + qbase + (size_t)(qt_lo<<6)*1024 + 32 + quad*8);

  floatx4 oa_hi[4], oa_lo[4];
  #pragma unroll
  for (int i=0;i<4;i++){ oa_hi[i] = (floatx4)0.0f; oa_lo[i] = (floatx4)0.0f; }
  float li_hi = 0.0f, li_lo = 0.0f;

  const unsigned short* Kbh = Kg + ((size_t)(b<<11))*1024 + (h<<6);
  const unsigned short* Vbh = Vt + (size_t)bh*64*2048;
  unsigned short* Pw0 = &PT[wave][0][0];
  unsigned short* Pw1 = &PT[wave][1][0];

  const int slot0 = wave*128 + lane;
  const int krow0 = slot0 >> 3, kc0 = (slot0 & 7) ^ (krow0 & 7);
  const int slot1 = slot0 + 64;
  const int krow1 = slot1 >> 3, kc1 = (slot1 & 7) ^ (krow1 & 7);

  auto softmax_P = [&](floatx4* sa, float& li, unsigned short* Pbuf, bool diag){
    if (diag){
      const int qrow = (wave<<4) + l15;
      #pragma unroll
      for (int tj=0;tj<4;tj++)
        #pragma unroll
        for (int r=0;r<4;r++)
          if (tj*16 + quad*4 + r > qrow) sa[tj][r] = -1e30f;
    }
    float rs = 0.0f;
    #pragma unroll
    for (int tj=0;tj<4;tj++)
      #pragma unroll
      for (int r=0;r<4;r++){
        const float p = __builtin_amdgcn_exp2f(sa[tj][r] - FM);
        sa[tj][r] = p;
        rs += p;
      }
    li += rs;
    #pragma unroll
    for (int tj=0;tj<4;tj++){
      uint2 pkd = make_uint2(pk2(sa[tj][0], sa[tj][1]), pk2(sa[tj][2], sa[tj][3]));
      *(uint2*)(Pbuf + l15*68 + tj*16 + quad*4) = pkd;
    }
  };

  for (int kt = 0; kt <= qt_hi; ++kt){
    gl_lds16(Kbh + (size_t)((kt<<6) + krow0)*1024 + kc0*8, Ks + wave*1024);
    gl_lds16(Kbh + (size_t)((kt<<6) + krow1)*1024 + kc1*8, Ks + wave*1024 + 512);
    gl_lds16(Vbh + (size_t)krow0*2048 + (kt<<6) + kc0*8, Vs + wave*1024);
    gl_lds16(Vbh + (size_t)krow1*2048 + (kt<<6) + kc1*8, Vs + wave*1024 + 512);
    __syncthreads();

    if (kt <= qt_lo){
      floatx4 sh[4], sl[4];
      __builtin_amdgcn_s_setprio(1);
      #pragma unroll
      for (int tj=0;tj<4;tj++){
        sh[tj] = (floatx4)0.0f; sl[tj] = (floatx4)0.0f;
        #pragma unroll
        for (int ks=0;ks<2;ks++){
          const int n = tj*16 + l15;
          const int c = (ks*4 + quad) ^ (n & 7);
          const bf16x8 kf = *(const bf16x8*)(Ks + n*64 + c*8);
          sh[tj] = __builtin_amdgcn_mfma_f32_16x16x32_bf16(kf, qf_hi[ks], sh[tj], 0,0,0);
          sl[tj] = __builtin_amdgcn_mfma_f32_16x16x32_bf16(kf, qf_lo[ks], sl[tj], 0,0,0);
        }
      }
      __builtin_amdgcn_s_setprio(0);
      softmax_P(sh, li_hi, Pw0, false);
      softmax_P(sl, li_lo, Pw1, kt == qt_lo);
      __builtin_amdgcn_s_setprio(1);
      #pragma unroll
      for (int ks2=0;ks2<2;ks2++){
        const bf16x8 pfh = *(const bf16x8*)(Pw0 + l15*68 + ks2*32 + quad*8);
        const bf16x8 pfl = *(const bf16x8*)(Pw1 + l15*68 + ks2*32 + quad*8);
        #pragma unroll
        for (int tn=0;tn<4;tn++){
          const int n2 = tn*16 + l15;
          const int c = (ks2*4 + quad) ^ (n2 & 7);
          const bf16x8 vf = *(const bf16x8*)(Vs + n2*64 + c*8);
          oa_hi[tn] = __builtin_amdgcn_mfma_f32_16x16x32_bf16(vf, pfh, oa_hi[tn], 0,0,0);
          oa_lo[tn] = __builtin_amdgcn_mfma_f32_16x16x32_bf16(vf, pfl, oa_lo[tn], 0,0,0);
        }
      }
      __builtin_amdgcn_s_setprio(0);
    } else {
      floatx4 sh[4];
      __builtin_amdgcn_s_setprio(1);
      #pragma unroll
      for (int tj=0;tj<4;tj++){
        sh[tj] = (floatx4)0.0f;
        #pragma unroll
        for (int ks=0;ks<2;ks++){
          const int n = tj*16 + l15;
          const int c = (ks*4 + quad) ^ (n & 7);
          const bf16x8 kf = *(const bf16x8*)(Ks + n*64 + c*8);
          sh[tj] = __builtin_amdgcn_mfma_f32_16x16x32_bf16(kf, qf_hi[ks], sh[tj], 0,0,0);
        }
      }
      __builtin_amdgcn_s_setprio(0);
      softmax_P(sh, li_hi, Pw0, kt == qt_hi);
      __builtin_amdgcn_s_setprio(1);
      #pragma unroll
      for (int ks2=0;ks2<2;ks2++){
        const bf16x8 pfh = *(const bf16x8*)(Pw0 + l15*68 + ks2*32 + quad*8);
        #pragma unroll
        for (int tn=0;tn<4;tn++){
          const int n2 = tn*16 + l15;
          const int c = (ks2*4 + quad) ^ (n2 & 7);
          const bf16x8 vf = *(const bf16x8*)(Vs + n2*64 + c*8);
          oa_hi[tn] = __builtin_amdgcn_mfma_f32_16x16x32_bf16(vf, pfh, oa_hi[tn], 0,0,0);
        }
      }
      __builtin_amdgcn_s_setprio(0);
    }
    __syncthreads();
  }

  li_hi += __shfl_xor(li_hi, 16, 64);
  li_hi += __shfl_xor(li_hi, 32, 64);
  li_lo += __shfl_xor(li_lo, 16, 64);
  li_lo += __shfl_xor(li_lo, 32, 64);
  {
    const float inv = 1.0f / li_hi;
    unsigned short* Orow = O + (size_t)((b<<11) + (qt_hi<<6) + (wave<<4) + l15)*1024 + (h<<6);
    #pragma unroll
    for (int tn=0;tn<4;tn++){
      uint2 pkd = make_uint2(pk2(oa_hi[tn][0]*inv, oa_hi[tn][1]*inv),
                             pk2(oa_hi[tn][2]*inv, oa_hi[tn][3]*inv));
      *(uint2*)(Orow + tn*16 + quad*4) = pkd;
    }
  }
  {
    const float inv = 1.0f / li_lo;
    unsigned short* Orow = O + (size_t)((b<<11) + (qt_lo<<6) + (wave<<4) + l15)*1024 + (h<<6);
    #pragma unroll
    for (int tn=0;tn<4;tn++){
      uint2 pkd = make_uint2(pk2(oa_lo[tn][0]*inv, oa_lo[tn][1]*inv),
                             pk2(oa_lo[tn][2]*inv, oa_lo[tn][3]*inv));
      *(uint2*)(Orow + tn*16 + quad*4) = pkd;
    }
  }
}

// ---------------- residual + LayerNorm (fp32 second source) ----------------
__global__ __launch_bounds__(256) void ln_res(const float* __restrict__ a,
                                              const float* __restrict__ bsrc,
                                              const float* __restrict__ g,
                                              const float* __restrict__ be,
                                              float* __restrict__ of,
                                              unsigned short* __restrict__ ob){
  __shared__ float red1[4], red2[4];
  const int row = blockIdx.x, t = threadIdx.x;
  const int wave = t >> 6, lane = t & 63;
  const float4 va = *(const float4*)(a + (size_t)row*1024 + t*4);
  const float4 vb = *(const float4*)(bsrc + (size_t)row*1024 + t*4);
  float xs[4] = {va.x+vb.x, va.y+vb.y, va.z+vb.z, va.w+vb.w};
  float s = xs[0]+xs[1]+xs[2]+xs[3];
  #pragma unroll
  for (int d=1; d<64; d<<=1) s += __shfl_xor(s, d, 64);
  if (lane==0) red1[wave] = s;
  __syncthreads();
  const float mean = (red1[0]+red1[1]+red1[2]+red1[3]) * (1.0f/1024.0f);
  float vsum = 0.0f;
  #pragma unroll
  for (int i=0;i<4;i++){ const float d = xs[i]-mean; vsum += d*d; }
  #pragma unroll
  for (int d=1; d<64; d<<=1) vsum += __shfl_xor(vsum, d, 64);
  if (lane==0) red2[wave] = vsum;
  __syncthreads();
  const float var = (red2[0]+red2[1]+red2[2]+red2[3]) * (1.0f/1024.0f);
  const float rs = rsqrtf(var + 1e-5f);
  const float4 gg = *(const float4*)(g + t*4);
  const float4 bb = *(const float4*)(be + t*4);
  float y[4];
  y[0] = (xs[0]-mean)*rs*gg.x + bb.x;
  y[1] = (xs[1]-mean)*rs*gg.y + bb.y;
  y[2] = (xs[2]-mean)*rs*gg.z + bb.z;
  y[3] = (xs[3]-mean)*rs*gg.w + bb.w;
  if (of){
    float4 o4; o4.x=y[0]; o4.y=y[1]; o4.z=y[2]; o4.w=y[3];
    *(float4*)(of + (size_t)row*1024 + t*4) = o4;
  }
  if (ob){
    ushort4v u = { f2bs(y[0]), f2bs(y[1]), f2bs(y[2]), f2bs(y[3]) };
    *(ushort4v*)(ob + (size_t)row*1024 + t*4) = u;
  }
}

// ---------------- residual + LayerNorm (two bf16 partial sources) ----------------
__global__ __launch_bounds__(256) void ln_res2(const float* __restrict__ a,
                                               const unsigned short* __restrict__ p0,
                                               const unsigned short* __restrict__ p1,
                                               const float* __restrict__ g,
                                               const float* __restrict__ be,
                                               float* __restrict__ of){
  __shared__ float red1[4], red2[4];
  const int row = blockIdx.x, t = threadIdx.x;
  const int wave = t >> 6, lane = t & 63;
  const float4 va = *(const float4*)(a + (size_t)row*1024 + t*4);
  const ushort4v u0 = *(const ushort4v*)(p0 + (size_t)row*1024 + t*4);
  const ushort4v u1 = *(const ushort4v*)(p1 + (size_t)row*1024 + t*4);
  float xs[4] = { va.x + bs2f(u0[0]) + bs2f(u1[0]),
                  va.y + bs2f(u0[1]) + bs2f(u1[1]),
                  va.z + bs2f(u0[2]) + bs2f(u1[2]),
                  va.w + bs2f(u0[3]) + bs2f(u1[3]) };
  float s = xs[0]+xs[1]+xs[2]+xs[3];
  #pragma unroll
  for (int d=1; d<64; d<<=1) s += __shfl_xor(s, d, 64);
  if (lane==0) red1[wave] = s;
  __syncthreads();
  const float mean = (red1[0]+red1[1]+red1[2]+red1[3]) * (1.0f/1024.0f);
  float vsum = 0.0f;
  #pragma unroll
  for (int i=0;i<4;i++){ const float d = xs[i]-mean; vsum += d*d; }
  #pragma unroll
  for (int d=1; d<64; d<<=1) vsum += __shfl_xor(vsum, d, 64);
  if (lane==0) red2[wave] = vsum;
  __syncthreads();
  const float var = (red2[0]+red2[1]+red2[2]+red2[3]) * (1.0f/1024.0f);
  const float rs = rsqrtf(var + 1e-5f);
  const float4 gg = *(const float4*)(g + t*4);
  const float4 bb = *(const float4*)(be + t*4);
  float4 o4;
  o4.x = (xs[0]-mean)*rs*gg.x + bb.x;
  o4.y = (xs[1]-mean)*rs*gg.y + bb.y;
  o4.z = (xs[2]-mean)*rs*gg.z + bb.z;
  o4.w = (xs[3]-mean)*rs*gg.w + bb.w;
  *(float4*)(of + (size_t)row*1024 + t*4) = o4;
}

extern "C" void kernel_launch(void* const* d_in, const int* in_sizes, int n_in,
                              void* d_out, int out_size, void* d_ws, size_t ws_size,
                              hipStream_t stream){
  (void)in_sizes; (void)n_in; (void)out_size; (void)ws_size;
  const float* x  = (const float*)d_in[0];
  const float* wq = (const float*)d_in[1];
  const float* bq = (const float*)d_in[2];
  const float* wk = (const float*)d_in[3];
  const float* bk = (const float*)d_in[4];
  const float* wv = (const float*)d_in[5];
  const float* bv = (const float*)d_in[6];
  const float* wo = (const float*)d_in[7];
  const float* bo = (const float*)d_in[8];
  const float* w1 = (const float*)d_in[9];
  const float* b1 = (const float*)d_in[10];
  const float* w2 = (const float*)d_in[11];
  const float* b2 = (const float*)d_in[12];
  const float* g1 = (const float*)d_in[13];
  const float* be1= (const float*)d_in[14];
  const float* g2 = (const float*)d_in[15];
  const float* be2= (const float*)d_in[16];
  float* out = (float*)d_out;

  char* ws = (char*)d_ws;
  size_t off = 0;
  auto take = [&](size_t bytes)->char*{
    char* p = ws + off; off += (bytes + 255) & ~(size_t)255; return p;
  };
  unsigned short* Xb  = (unsigned short*)take(8192UL*1024*2);
  unsigned short* Qb  = (unsigned short*)take(8192UL*1024*2);
  unsigned short* Kb  = (unsigned short*)take(8192UL*1024*2);
  unsigned short* Vtb = (unsigned short*)take(8192UL*1024*2);
  unsigned short* Ob  = (unsigned short*)take(8192UL*1024*2);
  unsigned short* Midb= Qb;                    // alias: spans Qb..Ob (64 MB), dead by FFN1
  unsigned short* Vtok= (unsigned short*)take(8192UL*1024*2);
  unsigned short* Wqkv= (unsigned short*)take(3072UL*1024*2);
  float*          Bqkv= (float*)take(3072UL*4);
  unsigned short* Wot = (unsigned short*)take(1024UL*1024*2);
  unsigned short* W1t = (unsigned short*)take(4096UL*1024*2);
  unsigned short* W2t = (unsigned short*)take(1024UL*4096*2);
  float*          C1  = (float*)take(8192UL*1024*4);
  unsigned short* F0  = (unsigned short*)C1;   // alias: C1 dead after LN1; F0+F1 = 32 MB
  unsigned short* F1  = F0 + 8192UL*1024;
  float*          Hf  = (float*)take(8192UL*1024*4);
  unsigned short* Hb  = (unsigned short*)take(8192UL*1024*2);

  // 1. fused prep: cvt_x + pack_qkv + 3x transpose_pack (one launch)
  prep<<<14336, 256, 0, stream>>>(x, Xb, wq, wk, wv, bq, bk, bv,
                                  Wqkv, Bqkv, wo, Wot, w1, W1t, w2, W2t);

  // 2. fused QKV projection (PIPE=1 counted schedule) + V transpose
  gemm256<3,1><<<12*32, 512, 0, stream>>>(Wqkv, Xb, Bqkv, Qb, Kb, Vtok, 1024, 1024);
  vtrans<<<dim3(32,64), 256, 0, stream>>>(Vtok, Vtb);

  // 3. causal flash attention (gl_lds staging, fixed-max softmax, 4 blocks/CU)
  attn<<<1024, 256, 0, stream>>>(Qb, Kb, Vtb, Ob);

  // 4. output projection (fp32, 128^2 kernel) -> residual + LN1
  gemm_tn<1><<<8*64, 256, 0, stream>>>(Wot, Ob, bo, C1, nullptr, nullptr, 1024, 1024, 1024);
  ln_res<<<8192, 256, 0, stream>>>(x, C1, g1, be1, Hf, Hb);

  // 5. FFN: gelu(h@w1+b1) -> Midb (PIPE=0); w2 split-K x2 -> bf16 partials (PIPE=1)
  gemm256<2,0><<<16*32, 512, 0, stream>>>(W1t, Hb, b1, Midb, nullptr, nullptr, 1024, 1024);
  gemm256<4,1><<<dim3(4*32,1,2), 512, 0, stream>>>(W2t, Midb, b2, F0, F1, nullptr, 4096, 2048);
  ln_res2<<<8192, 256, 0, stream>>>(Hf, F0, F1, g2, be2, out);
}

// Round 8
// 495.342 us; speedup vs baseline: 1.1343x; 1.0144x over previous
//
#include <hip/hip_runtime.h>
#include <hip/hip_bf16.h>
#include <math.h>

typedef __bf16 bf16x8 __attribute__((ext_vector_type(8)));
typedef float floatx4 __attribute__((ext_vector_type(4)));
typedef unsigned short ushort8 __attribute__((ext_vector_type(8)));
typedef unsigned short ushort4v __attribute__((ext_vector_type(4)));

__device__ __forceinline__ unsigned short f2bs(float f){
  union { float f; unsigned u; } v; v.f = f;
  unsigned r = v.u + 0x7fffu + ((v.u >> 16) & 1u);
  return (unsigned short)(r >> 16);
}
__device__ __forceinline__ float bs2f(unsigned short s){
  union { unsigned u; float f; } v; v.u = ((unsigned)s) << 16; return v.f;
}
// packed f32x2 -> bf16x2 (RNE)
__device__ __forceinline__ unsigned pk2(float a, float b){
  union { __hip_bfloat162 h; unsigned u; } cv;
  cv.h = __float22bfloat162_rn(make_float2(a, b));
  return cv.u;
}
__device__ __forceinline__ void gl_lds16(const void* g, void* l){
  __builtin_amdgcn_global_load_lds(
      (const __attribute__((address_space(1))) void*)g,
      (__attribute__((address_space(3))) void*)l,
      16, 0, 0);
}

// ---------------- fused prep: cvt_x + pack_qkv + 3x transpose_pack ----------------
// One launch instead of five. Flat 1D grid, whole blocks per path:
//   [0,8192):      x fp32 -> Xb bf16
//   [8192,9728):   pack wq/wk/wv -> Wqkv_t [3072][1024] + bias
//   [9728,10240):  wo  [1024][1024] -> Wot  (bf16 [C][R])
//   [10240,12288): w1  [1024][4096] -> W1t
//   [12288,14336): w2  [4096][1024] -> W2t
__global__ __launch_bounds__(256) void prep(
    const float* __restrict__ x,  unsigned short* __restrict__ Xb,
    const float* __restrict__ wq, const float* __restrict__ wk,
    const float* __restrict__ wv, const float* __restrict__ bq,
    const float* __restrict__ bk, const float* __restrict__ bv,
    unsigned short* __restrict__ Wqkv, float* __restrict__ Bqkv,
    const float* __restrict__ wo, unsigned short* __restrict__ Wot,
    const float* __restrict__ w1, unsigned short* __restrict__ W1t,
    const float* __restrict__ w2, unsigned short* __restrict__ W2t){
  __shared__ float tile[32][65];
  const int blk = blockIdx.x, t = threadIdx.x;

  if (blk < 8192){                       // ---- cvt_x ----
    const int i = (blk*256 + t)*4;
    const float4 v = *(const float4*)(x + i);
    ushort4v u = { f2bs(v.x), f2bs(v.y), f2bs(v.z), f2bs(v.w) };
    *(ushort4v*)(Xb + i) = u;
    return;
  }

  if (blk < 9728){                       // ---- pack_qkv ----
    const int p = blk - 8192;
    const int dt = p & 31, h = (p>>5)&15, sel = p>>9;
    const float* src = (sel==0 ? wq : (sel==1 ? wk : wv)) + (size_t)h*65536;
    const int d0 = dt*32;
    {
      const int r = t >> 3, cc = (t & 7)*8;
      const float* pp = src + (size_t)(d0+r)*64 + cc;
      const float4 v0 = *(const float4*)pp;
      const float4 v1 = *(const float4*)(pp+4);
      tile[r][cc+0]=v0.x; tile[r][cc+1]=v0.y; tile[r][cc+2]=v0.z; tile[r][cc+3]=v0.w;
      tile[r][cc+4]=v1.x; tile[r][cc+5]=v1.y; tile[r][cc+6]=v1.z; tile[r][cc+7]=v1.w;
    }
    __syncthreads();
    const int f = t >> 2, rr = (t & 3)*8;
    ushort8 u;
    #pragma unroll
    for (int j=0;j<8;j++) u[j] = f2bs(tile[rr+j][f]);
    const size_t n = (size_t)sel*1024 + h*64 + f;
    *(ushort8*)(Wqkv + n*1024 + d0 + rr) = u;
    if (dt==0 && t<64){
      const float* bs = (sel==0 ? bq : (sel==1 ? bk : bv)) + h*64;
      Bqkv[sel*1024 + h*64 + t] = bs[t];
    }
    return;
  }

  // ---- transpose_pack (3 matrices) ----
  const float* src; unsigned short* dst; int R, C, bx, by;
  if (blk < 10240){ const int q = blk-9728;  src=wo; dst=Wot; R=1024; C=1024; bx=q&15; by=q>>4; }
  else if (blk < 12288){ const int q = blk-10240; src=w1; dst=W1t; R=1024; C=4096; bx=q&63; by=q>>6; }
  else { const int q = blk-12288; src=w2; dst=W2t; R=4096; C=1024; bx=q&15; by=q>>4; }
  const int r0 = by*32, c0 = bx*64;
  {
    const int r = t >> 3, cc = (t & 7)*8;
    const float* p = src + (size_t)(r0+r)*C + c0 + cc;
    const float4 v0 = *(const float4*)p;
    const float4 v1 = *(const float4*)(p+4);
    tile[r][cc+0]=v0.x; tile[r][cc+1]=v0.y; tile[r][cc+2]=v0.z; tile[r][cc+3]=v0.w;
    tile[r][cc+4]=v1.x; tile[r][cc+5]=v1.y; tile[r][cc+6]=v1.z; tile[r][cc+7]=v1.w;
  }
  __syncthreads();
  const int f = t >> 2, rr = (t & 3)*8;
  ushort8 u;
  #pragma unroll
  for (int j=0;j<8;j++) u[j] = f2bs(tile[rr+j][f]);
  *(ushort8*)(dst + (size_t)(c0+f)*R + r0 + rr) = u;
}

// ---------------- transposed-orientation bf16 GEMM (128^2, kept for Wo) ----------------
template<int MODE>
__global__ __launch_bounds__(256, 4)
void gemm_tn(const unsigned short* __restrict__ A,
             const unsigned short* __restrict__ Bt,
             const float* __restrict__ bias,
             void* __restrict__ out0,
             void* __restrict__ out1,
             void* __restrict__ out2,
             int K, int OW, int klen){
  __shared__ __align__(16) unsigned short As[128*32];
  __shared__ __align__(16) unsigned short Bs[128*32];
  const int tid = threadIdx.x;
  const int wave = tid >> 6, lane = tid & 63;
  const int quad = lane >> 4, l15 = lane & 15;
  const int lin = blockIdx.x;
  const int n0 = (lin & 63) << 7;
  const int m0 = (lin >> 6) << 7;
  const int kz = blockIdx.z;
  const int kbase = kz * klen;
  const int wr = (wave >> 1) << 6, wc = (wave & 1) << 6;

  floatx4 acc[4][4];
  #pragma unroll
  for (int i=0;i<4;i++)
    #pragma unroll
    for (int j=0;j<4;j++) acc[i][j] = (floatx4)0.0f;

  const unsigned short* gA[2];
  const unsigned short* gB[2];
  int lofs[2];
  #pragma unroll
  for (int r2=0;r2<2;r2++){
    const int slot = r2*256 + tid;
    const int rp = slot >> 3, rem = slot & 7;
    const int row = rp*2 + (rem >> 2);
    const int kc = (rem & 3) ^ (rp & 3);
    gA[r2] = A  + (size_t)(m0 + row)*K + kbase + kc*8;
    gB[r2] = Bt + (size_t)(n0 + row)*K + kbase + kc*8;
    lofs[r2] = slot*8;
  }
  int aofs[4], bofs[4];
  #pragma unroll
  for (int t=0;t<4;t++){
    const int ra = wr + t*16 + l15;
    aofs[t] = (ra>>1)*64 + (ra&1)*32 + ((quad ^ ((ra>>1)&3))<<3);
    const int rb = wc + t*16 + l15;
    bofs[t] = (rb>>1)*64 + (rb&1)*32 + ((quad ^ ((rb>>1)&3))<<3);
  }

  for (int k0 = 0; k0 < klen; k0 += 32){
    gl_lds16(gA[0] + k0, As + lofs[0]);
    gl_lds16(gA[1] + k0, As + lofs[1]);
    gl_lds16(gB[0] + k0, Bs + lofs[0]);
    gl_lds16(gB[1] + k0, Bs + lofs[1]);
    __syncthreads();
    bf16x8 af[4];
    #pragma unroll
    for (int t=0;t<4;t++) af[t] = *(const bf16x8*)(&As[aofs[t]]);
    #pragma unroll
    for (int j=0;j<4;j++){
      const bf16x8 bv = *(const bf16x8*)(&Bs[bofs[j]]);
      #pragma unroll
      for (int i=0;i<4;i++)
        acc[i][j] = __builtin_amdgcn_mfma_f32_16x16x32_bf16(af[i], bv, acc[i][j], 0,0,0);
    }
    __syncthreads();
  }

  #pragma unroll
  for (int i=0;i<4;i++){
    const int row0 = m0 + wr + i*16 + quad*4;
    float4 b4 = make_float4(0.f,0.f,0.f,0.f);
    if (MODE != 4 || kz == 0) b4 = *(const float4*)(bias + row0);
    #pragma unroll
    for (int j=0;j<4;j++){
      const int tok = n0 + wc + j*16 + l15;
      float v0 = acc[i][j][0] + b4.x;
      float v1 = acc[i][j][1] + b4.y;
      float v2 = acc[i][j][2] + b4.z;
      float v3 = acc[i][j][3] + b4.w;
      if (MODE == 1){
        float4 o4; o4.x=v0; o4.y=v1; o4.z=v2; o4.w=v3;
        *(float4*)((float*)out0 + (size_t)tok*OW + row0) = o4;
      } else if (MODE == 2){
        float vv[4] = {v0,v1,v2,v3};
        #pragma unroll
        for (int r=0;r<4;r++){
          const float v = vv[r];
          const float u = 0.7978845608f*v*(1.0f + 0.044715f*v*v);
          const float e = __builtin_amdgcn_exp2f(u * 2.885390082f);
          vv[r] = 0.5f*v*(1.0f + (1.0f - 2.0f/(1.0f + e)));
        }
        uint2 pkd = make_uint2(pk2(vv[0], vv[1]), pk2(vv[2], vv[3]));
        *(uint2*)((unsigned short*)out0 + (size_t)tok*4096 + row0) = pkd;
      } else if (MODE == 4){
        uint2 pkd = make_uint2(pk2(v0, v1), pk2(v2, v3));
        unsigned short* o = (unsigned short*)(kz ? out1 : out0);
        *(uint2*)(o + (size_t)tok*1024 + row0) = pkd;
      } else {
        if (row0 < 1024){
          const float s = 0.18033688011112042f;
          uint2 pkd = make_uint2(pk2(v0*s, v1*s), pk2(v2*s, v3*s));
          *(uint2*)((unsigned short*)out0 + (size_t)tok*1024 + row0) = pkd;
        } else if (row0 < 2048){
          uint2 pkd = make_uint2(pk2(v0, v1), pk2(v2, v3));
          *(uint2*)((unsigned short*)out1 + (size_t)tok*1024 + (row0-1024)) = pkd;
        } else {
          uint2 pkd = make_uint2(pk2(v0, v1), pk2(v2, v3));
          *(uint2*)((unsigned short*)out2 + (size_t)tok*1024 + (row0-2048)) = pkd;
        }
      }
    }
  }
}

// ---------------- 256x256 pipelined bf16 GEMM, single schedule ----------------
// SINGLE-VARIANT BUILD (rule #19: co-compiled template variants perturb each
// other's codegen; all-PIPE1 single-variant build measured 500us total in R4
// vs 502-521 for mixed/all-PIPE0). Counted-lgkm schedule, 2 barriers/tile,
// reads issued one phase ahead of their MFMA; counted vmcnt(4) per tile.
// Dedup'd LDS reads: each unique fragment read ONCE per K-tile (24 reads).
#define VMCNT4 asm volatile("s_waitcnt vmcnt(4)" ::: "memory")
#define VMCNT0 asm volatile("s_waitcnt vmcnt(0)" ::: "memory")
#define TAILW { if (tg < NT-2) VMCNT4; else VMCNT0; }
#define LGKM4 { asm volatile("s_waitcnt lgkmcnt(4)" ::: "memory"); __builtin_amdgcn_sched_barrier(0); }
#define LGKM8 { asm volatile("s_waitcnt lgkmcnt(8)" ::: "memory"); __builtin_amdgcn_sched_barrier(0); }
#define LGKM0 { asm volatile("s_waitcnt lgkmcnt(0)" ::: "memory"); __builtin_amdgcn_sched_barrier(0); }

#define STAGE_A(T, H) { const int T_ = (T); if (T_ < NT){                     \
    unsigned short* l_ = lds + (T_&1)*32768 + (H)*8192;                       \
    const int ko_ = kbase + (T_<<6);                                          \
    gl_lds16(srcA##H##_0 + ko_, l_ + ch0*8);                                  \
    gl_lds16(srcA##H##_1 + ko_, l_ + ch1*8); } }
#define STAGE_B(T, H) { const int T_ = (T); if (T_ < NT){                     \
    unsigned short* l_ = lds + (T_&1)*32768 + 16384 + (H)*8192;               \
    const int ko_ = kbase + (T_<<6);                                          \
    gl_lds16(srcB##H##_0 + ko_, l_ + ch0*8);                                  \
    gl_lds16(srcB##H##_1 + ko_, l_ + ch1*8); } }

#define MFMA_Q(AF, BF, MH, NH)                                                \
    __builtin_amdgcn_s_setprio(1);                                            \
    _Pragma("unroll")                                                         \
    for (int k_=0;k_<2;k_++)                                                  \
      _Pragma("unroll")                                                       \
      for (int m_=0;m_<4;m_++)                                                \
        _Pragma("unroll")                                                     \
        for (int n_=0;n_<2;n_++)                                              \
          acc[(MH)*4+m_][(NH)*2+n_] = __builtin_amdgcn_mfma_f32_16x16x32_bf16( \
              AF[m_][k_], BF[n_][k_], acc[(MH)*4+m_][(NH)*2+n_], 0,0,0);      \
    __builtin_amdgcn_s_setprio(0);

#define RD_A(DST, BASE)                                                       \
    _Pragma("unroll")                                                         \
    for (int m_=0;m_<4;m_++)                                                  \
      _Pragma("unroll")                                                       \
      for (int k_=0;k_<2;k_++) DST[m_][k_] = *(const bf16x8*)((BASE) + aoff[m_][k_]);
#define RD_B(DST, BASE)                                                       \
    _Pragma("unroll")                                                         \
    for (int n_=0;n_<2;n_++)                                                  \
      _Pragma("unroll")                                                       \
      for (int k_=0;k_<2;k_++) DST[n_][k_] = *(const bf16x8*)((BASE) + boff[n_][k_]);

template<int MODE>
__global__ __launch_bounds__(512, 2)
void gemm256(const unsigned short* __restrict__ A,
             const unsigned short* __restrict__ Bt,
             const float* __restrict__ bias,
             void* __restrict__ out0,
             void* __restrict__ out1,
             void* __restrict__ out2,
             int K, int klen){
  __shared__ __align__(16) unsigned short lds[65536];   // 128 KiB
  const int tid = threadIdx.x;
  const int wave = tid >> 6, lane = tid & 63;
  const int quad = lane >> 4, l15 = lane & 15;
  const int wm = wave >> 2, wn = wave & 3;
  const int lin = blockIdx.x;
  const int n0 = (lin & 31) << 8;     // token tile (fast dim -> pins XCD)
  const int m0 = (lin >> 5) << 8;     // weight tile
  const int kz = blockIdx.z;
  const int kbase = kz * klen;
  const int NT = klen >> 6;

  const int r0 = tid >> 3;
  const int r1 = r0 + 64;
  const int g0 = (tid & 7) ^ (r0 & 7);
  const int ch0 = tid, ch1 = tid + 512;

  const unsigned short* srcA0_0 = A  + (size_t)(m0 +       r0)*K + g0*8;
  const unsigned short* srcA0_1 = A  + (size_t)(m0 +       r1)*K + g0*8;
  const unsigned short* srcA1_0 = A  + (size_t)(m0 + 128 + r0)*K + g0*8;
  const unsigned short* srcA1_1 = A  + (size_t)(m0 + 128 + r1)*K + g0*8;
  const unsigned short* srcB0_0 = Bt + (size_t)(n0 +       r0)*K + g0*8;
  const unsigned short* srcB0_1 = Bt + (size_t)(n0 +       r1)*K + g0*8;
  const unsigned short* srcB1_0 = Bt + (size_t)(n0 + 128 + r0)*K + g0*8;
  const unsigned short* srcB1_1 = Bt + (size_t)(n0 + 128 + r1)*K + g0*8;

  const int xr = l15 & 7;
  int aoff[4][2], boff[2][2];
  #pragma unroll
  for (int m=0;m<4;m++){
    const int rh = wm*64 + m*16 + l15;
    #pragma unroll
    for (int k=0;k<2;k++)
      aoff[m][k] = rh*64 + (((k*4 + quad) ^ xr) << 3);
  }
  #pragma unroll
  for (int n=0;n<2;n++){
    const int rb = wn*32 + n*16 + l15;
    #pragma unroll
    for (int k=0;k<2;k++)
      boff[n][k] = rb*64 + (((k*4 + quad) ^ xr) << 3);
  }

  floatx4 acc[8][4];
  #pragma unroll
  for (int i=0;i<8;i++)
    #pragma unroll
    for (int j=0;j<4;j++) acc[i][j] = (floatx4)0.0f;

  bf16x8 af0[4][2], af1[4][2], bf0[2][2], bf1[2][2];

  // prologue: tile0 fully + tile1 {B0,A0}; drain tile0 (leave 4 in flight)
  STAGE_B(0,0); STAGE_A(0,0); STAGE_A(0,1); STAGE_B(0,1);
  STAGE_B(1,0); STAGE_A(1,0);
  VMCNT4;
  __builtin_amdgcn_s_barrier();
  RD_A(af0, lds);
  RD_B(bf0, lds + 16384);

  for (int tg = 0; tg < NT; ++tg){
    const int d = tg & 1;
    const unsigned short* A1b = lds + d*32768 + 8192;
    const unsigned short* B1b = lds + d*32768 + 16384 + 8192;

    // P1: issue bf1(t) reads; stage A1(t+1); drain af0/bf0; MFMA (0,0)
    RD_B(bf1, B1b);
    STAGE_A(tg+1, 1);
    LGKM4;
    MFMA_Q(af0, bf0, 0, 0);

    // P2: issue af1(t) reads; stage B1(t+1); drain bf1; MFMA (0,1)
    RD_A(af1, A1b);
    STAGE_B(tg+1, 1);
    LGKM8;
    MFMA_Q(af0, bf1, 0, 1);
    __builtin_amdgcn_s_barrier();   // WAR gate for P3/P4 stages into buffer d

    // P3: stage B0(t+2); drain af1; MFMA (1,1)
    STAGE_B(tg+2, 0);
    LGKM0;
    MFMA_Q(af1, bf1, 1, 1);

    // P4: stage A0(t+2); counted vmcnt; barrier (tile t+1 ready);
    //     issue af0(t+1) reads; MFMA (1,0); issue bf0(t+1) reads
    STAGE_A(tg+2, 0);
    TAILW;
    __builtin_amdgcn_s_barrier();
    {
      const unsigned short* A0n = lds + (d^1)*32768;
      const unsigned short* B0n = A0n + 16384;
      if (tg+1 < NT){ RD_A(af0, A0n); }
      MFMA_Q(af1, bf0, 1, 0);
      if (tg+1 < NT){ RD_B(bf0, B0n); }
    }
  }

  // epilogue
  #pragma unroll
  for (int mh=0; mh<2; mh++){
    #pragma unroll
    for (int m=0; m<4; m++){
      const int row0 = m0 + mh*128 + wm*64 + m*16 + quad*4;
      float4 b4 = make_float4(0.f,0.f,0.f,0.f);
      if (MODE != 4 || kz == 0) b4 = *(const float4*)(bias + row0);
      #pragma unroll
      for (int nh=0; nh<2; nh++){
        #pragma unroll
        for (int n=0; n<2; n++){
          const int tok = n0 + nh*128 + wn*32 + n*16 + l15;
          const floatx4 a = acc[mh*4+m][nh*2+n];
          float v0 = a[0]+b4.x, v1 = a[1]+b4.y, v2 = a[2]+b4.z, v3 = a[3]+b4.w;
          if (MODE == 2){
            float vv[4] = {v0,v1,v2,v3};
            #pragma unroll
            for (int r=0;r<4;r++){
              const float v = vv[r];
              const float u = 0.7978845608f*v*(1.0f + 0.044715f*v*v);
              const float e = __builtin_amdgcn_exp2f(u * 2.885390082f);
              vv[r] = 0.5f*v*(1.0f + (1.0f - 2.0f/(1.0f + e)));
            }
            uint2 pkd = make_uint2(pk2(vv[0], vv[1]), pk2(vv[2], vv[3]));
            *(uint2*)((unsigned short*)out0 + (size_t)tok*4096 + row0) = pkd;
          } else if (MODE == 4){
            uint2 pkd = make_uint2(pk2(v0, v1), pk2(v2, v3));
            unsigned short* o = (unsigned short*)(kz ? out1 : out0);
            *(uint2*)(o + (size_t)tok*1024 + row0) = pkd;
          } else { // MODE 3: QKV split, Q scaled
            if (row0 < 1024){
              const float s = 0.18033688011112042f;
              uint2 pkd = make_uint2(pk2(v0*s, v1*s), pk2(v2*s, v3*s));
              *(uint2*)((unsigned short*)out0 + (size_t)tok*1024 + row0) = pkd;
            } else if (row0 < 2048){
              uint2 pkd = make_uint2(pk2(v0, v1), pk2(v2, v3));
              *(uint2*)((unsigned short*)out1 + (size_t)tok*1024 + (row0-1024)) = pkd;
            } else {
              uint2 pkd = make_uint2(pk2(v0, v1), pk2(v2, v3));
              *(uint2*)((unsigned short*)out2 + (size_t)tok*1024 + (row0-2048)) = pkd;
            }
          }
        }
      }
    }
  }
}

// ---------------- Vtok [b,s][h*64+f] -> Vt [bh][f][s] transpose ----------------
__global__ __launch_bounds__(256) void vtrans(const unsigned short* __restrict__ Vtok,
                                              unsigned short* __restrict__ Vt){
  __shared__ unsigned short tile[64][65];
  const int st = blockIdx.x, bh = blockIdx.y;
  const int b = bh >> 4, h = bh & 15;
  const int t = threadIdx.x;
  {
    const int r = t >> 2, cc = (t & 3) * 16;
    const unsigned short* src = Vtok + (size_t)((b<<11) + (st<<6) + r)*1024 + (h<<6) + cc;
    ushort8 u0 = *(const ushort8*)src;
    ushort8 u1 = *(const ushort8*)(src + 8);
    #pragma unroll
    for (int j=0;j<8;j++){ tile[r][cc+j] = u0[j]; tile[r][cc+8+j] = u1[j]; }
  }
  __syncthreads();
  const int f = t >> 2, ss = (t & 3) * 16;
  ushort8 w0, w1;
  #pragma unroll
  for (int j=0;j<8;j++){ w0[j] = tile[ss+j][f]; w1[j] = tile[ss+8+j][f]; }
  unsigned short* dst = Vt + (size_t)bh*64*2048 + (size_t)f*2048 + (st<<6) + ss;
  *(ushort8*)dst = w0;
  *(ushort8*)(dst + 8) = w1;
}

// ---------------- causal flash attention, fused pairs, FIXED-MAX softmax ----------------
// gl_lds staging (measured best vs reg-staging); (256,4): 4 blocks/CU, all
// 1024 blocks co-resident in one round; setprio around MFMA clusters.
__global__ __launch_bounds__(256, 4) void attn(const unsigned short* __restrict__ Q,
                                               const unsigned short* __restrict__ Kg,
                                               const unsigned short* __restrict__ Vt,
                                               unsigned short* __restrict__ O){
  __shared__ __align__(16) unsigned short Ks[64*64];
  __shared__ __align__(16) unsigned short Vs[64*64];
  __shared__ __align__(16) unsigned short PT[4][2][16*68];

  const int lin = blockIdx.x;
  const int bh = lin & 63;
  const int qt_lo = lin >> 6;          // 0..15
  const int qt_hi = 31 - qt_lo;        // 16..31
  const int b = bh >> 4, h = bh & 15;
  const int tid = threadIdx.x, wave = tid >> 6, lane = tid & 63;
  const int quad = lane >> 4, l15 = lane & 15;
  const float FM = 12.0f;              // fixed softmax max (log2 units)

  const size_t qbase = (size_t)((b<<11) + (wave<<4) + l15)*1024 + (h<<6);
  bf16x8 qf_hi[2], qf_lo[2];
  qf_hi[0] = *(const bf16x8*)(Q + qbase + (size_t)(qt_hi<<6)*1024 + quad*8);
  qf_hi[1] = *(const bf16x8*)(Q + qbase + (size_t)(qt_hi<<6)*1024 + 32 + quad*8);
  qf_lo[0] = *(const bf16x8*)(Q + qbase + (size_t)(qt_lo<<6)*1024 + quad*8);
  qf_lo[1] = *(const bf16x8*)(Q + qbase + (size_t)(qt_lo<<6)*1024 + 32 + quad*8);

  floatx4 oa_hi[4], oa_lo[4];
  #pragma unroll
  for (int i=0;i<4;i++){ oa_hi[i] = (floatx4)0.0f; oa_lo[i] = (floatx4)0.0f; }
  float li_hi = 0.0f, li_lo = 0.0f;

  const unsigned short* Kbh = Kg + ((size_t)(b<<11))*1024 + (h<<6);
  const unsigned short* Vbh = Vt + (size_t)bh*64*2048;
  unsigned short* Pw0 = &PT[wave][0][0];
  unsigned short* Pw1 = &PT[wave][1][0];

  const int slot0 = wave*128 + lane;
  const int krow0 = slot0 >> 3, kc0 = (slot0 & 7) ^ (krow0 & 7);
  const int slot1 = slot0 + 64;
  const int krow1 = slot1 >> 3, kc1 = (slot1 & 7) ^ (krow1 & 7);

  auto softmax_P = [&](floatx4* sa, float& li, unsigned short* Pbuf, bool diag){
    if (diag){
      const int qrow = (wave<<4) + l15;
      #pragma unroll
      for (int tj=0;tj<4;tj++)
        #pragma unroll
        for (int r=0;r<4;r++)
          if (tj*16 + quad*4 + r > qrow) sa[tj][r] = -1e30f;
    }
    float rs = 0.0f;
    #pragma unroll
    for (int tj=0;tj<4;tj++)
      #pragma unroll
      for (int r=0;r<4;r++){
        const float p = __builtin_amdgcn_exp2f(sa[tj][r] - FM);
        sa[tj][r] = p;
        rs += p;
      }
    li += rs;
    #pragma unroll
    for (int tj=0;tj<4;tj++){
      uint2 pkd = make_uint2(pk2(sa[tj][0], sa[tj][1]), pk2(sa[tj][2], sa[tj][3]));
      *(uint2*)(Pbuf + l15*68 + tj*16 + quad*4) = pkd;
    }
  };

  for (int kt = 0; kt <= qt_hi; ++kt){
    gl_lds16(Kbh + (size_t)((kt<<6) + krow0)*1024 + kc0*8, Ks + wave*1024);
    gl_lds16(Kbh + (size_t)((kt<<6) + krow1)*1024 + kc1*8, Ks + wave*1024 + 512);
    gl_lds16(Vbh + (size_t)krow0*2048 + (kt<<6) + kc0*8, Vs + wave*1024);
    gl_lds16(Vbh + (size_t)krow1*2048 + (kt<<6) + kc1*8, Vs + wave*1024 + 512);
    __syncthreads();

    if (kt <= qt_lo){
      floatx4 sh[4], sl[4];
      __builtin_amdgcn_s_setprio(1);
      #pragma unroll
      for (int tj=0;tj<4;tj++){
        sh[tj] = (floatx4)0.0f; sl[tj] = (floatx4)0.0f;
        #pragma unroll
        for (int ks=0;ks<2;ks++){
          const int n = tj*16 + l15;
          const int c = (ks*4 + quad) ^ (n & 7);
          const bf16x8 kf = *(const bf16x8*)(Ks + n*64 + c*8);
          sh[tj] = __builtin_amdgcn_mfma_f32_16x16x32_bf16(kf, qf_hi[ks], sh[tj], 0,0,0);
          sl[tj] = __builtin_amdgcn_mfma_f32_16x16x32_bf16(kf, qf_lo[ks], sl[tj], 0,0,0);
        }
      }
      __builtin_amdgcn_s_setprio(0);
      softmax_P(sh, li_hi, Pw0, false);
      softmax_P(sl, li_lo, Pw1, kt == qt_lo);
      __builtin_amdgcn_s_setprio(1);
      #pragma unroll
      for (int ks2=0;ks2<2;ks2++){
        const bf16x8 pfh = *(const bf16x8*)(Pw0 + l15*68 + ks2*32 + quad*8);
        const bf16x8 pfl = *(const bf16x8*)(Pw1 + l15*68 + ks2*32 + quad*8);
        #pragma unroll
        for (int tn=0;tn<4;tn++){
          const int n2 = tn*16 + l15;
          const int c = (ks2*4 + quad) ^ (n2 & 7);
          const bf16x8 vf = *(const bf16x8*)(Vs + n2*64 + c*8);
          oa_hi[tn] = __builtin_amdgcn_mfma_f32_16x16x32_bf16(vf, pfh, oa_hi[tn], 0,0,0);
          oa_lo[tn] = __builtin_amdgcn_mfma_f32_16x16x32_bf16(vf, pfl, oa_lo[tn], 0,0,0);
        }
      }
      __builtin_amdgcn_s_setprio(0);
    } else {
      floatx4 sh[4];
      __builtin_amdgcn_s_setprio(1);
      #pragma unroll
      for (int tj=0;tj<4;tj++){
        sh[tj] = (floatx4)0.0f;
        #pragma unroll
        for (int ks=0;ks<2;ks++){
          const int n = tj*16 + l15;
          const int c = (ks*4 + quad) ^ (n & 7);
          const bf16x8 kf = *(const bf16x8*)(Ks + n*64 + c*8);
          sh[tj] = __builtin_amdgcn_mfma_f32_16x16x32_bf16(kf, qf_hi[ks], sh[tj], 0,0,0);
        }
      }
      __builtin_amdgcn_s_setprio(0);
      softmax_P(sh, li_hi, Pw0, kt == qt_hi);
      __builtin_amdgcn_s_setprio(1);
      #pragma unroll
      for (int ks2=0;ks2<2;ks2++){
        const bf16x8 pfh = *(const bf16x8*)(Pw0 + l15*68 + ks2*32 + quad*8);
        #pragma unroll
        for (int tn=0;tn<4;tn++){
          const int n2 = tn*16 + l15;
          const int c = (ks2*4 + quad) ^ (n2 & 7);
          const bf16x8 vf = *(const bf16x8*)(Vs + n2*64 + c*8);
          oa_hi[tn] = __builtin_amdgcn_mfma_f32_16x16x32_bf16(vf, pfh, oa_hi[tn], 0,0,0);
        }
      }
      __builtin_amdgcn_s_setprio(0);
    }
    __syncthreads();
  }

  li_hi += __shfl_xor(li_hi, 16, 64);
  li_hi += __shfl_xor(li_hi, 32, 64);
  li_lo += __shfl_xor(li_lo, 16, 64);
  li_lo += __shfl_xor(li_lo, 32, 64);
  {
    const float inv = 1.0f / li_hi;
    unsigned short* Orow = O + (size_t)((b<<11) + (qt_hi<<6) + (wave<<4) + l15)*1024 + (h<<6);
    #pragma unroll
    for (int tn=0;tn<4;tn++){
      uint2 pkd = make_uint2(pk2(oa_hi[tn][0]*inv, oa_hi[tn][1]*inv),
                             pk2(oa_hi[tn][2]*inv, oa_hi[tn][3]*inv));
      *(uint2*)(Orow + tn*16 + quad*4) = pkd;
    }
  }
  {
    const float inv = 1.0f / li_lo;
    unsigned short* Orow = O + (size_t)((b<<11) + (qt_lo<<6) + (wave<<4) + l15)*1024 + (h<<6);
    #pragma unroll
    for (int tn=0;tn<4;tn++){
      uint2 pkd = make_uint2(pk2(oa_lo[tn][0]*inv, oa_lo[tn][1]*inv),
                             pk2(oa_lo[tn][2]*inv, oa_lo[tn][3]*inv));
      *(uint2*)(Orow + tn*16 + quad*4) = pkd;
    }
  }
}

// ---------------- residual + LayerNorm (fp32 second source) ----------------
__global__ __launch_bounds__(256) void ln_res(const float* __restrict__ a,
                                              const float* __restrict__ bsrc,
                                              const float* __restrict__ g,
                                              const float* __restrict__ be,
                                              float* __restrict__ of,
                                              unsigned short* __restrict__ ob){
  __shared__ float red1[4], red2[4];
  const int row = blockIdx.x, t = threadIdx.x;
  const int wave = t >> 6, lane = t & 63;
  const float4 va = *(const float4*)(a + (size_t)row*1024 + t*4);
  const float4 vb = *(const float4*)(bsrc + (size_t)row*1024 + t*4);
  float xs[4] = {va.x+vb.x, va.y+vb.y, va.z+vb.z, va.w+vb.w};
  float s = xs[0]+xs[1]+xs[2]+xs[3];
  #pragma unroll
  for (int d=1; d<64; d<<=1) s += __shfl_xor(s, d, 64);
  if (lane==0) red1[wave] = s;
  __syncthreads();
  const float mean = (red1[0]+red1[1]+red1[2]+red1[3]) * (1.0f/1024.0f);
  float vsum = 0.0f;
  #pragma unroll
  for (int i=0;i<4;i++){ const float d = xs[i]-mean; vsum += d*d; }
  #pragma unroll
  for (int d=1; d<64; d<<=1) vsum += __shfl_xor(vsum, d, 64);
  if (lane==0) red2[wave] = vsum;
  __syncthreads();
  const float var = (red2[0]+red2[1]+red2[2]+red2[3]) * (1.0f/1024.0f);
  const float rs = rsqrtf(var + 1e-5f);
  const float4 gg = *(const float4*)(g + t*4);
  const float4 bb = *(const float4*)(be + t*4);
  float y[4];
  y[0] = (xs[0]-mean)*rs*gg.x + bb.x;
  y[1] = (xs[1]-mean)*rs*gg.y + bb.y;
  y[2] = (xs[2]-mean)*rs*gg.z + bb.z;
  y[3] = (xs[3]-mean)*rs*gg.w + bb.w;
  if (of){
    float4 o4; o4.x=y[0]; o4.y=y[1]; o4.z=y[2]; o4.w=y[3];
    *(float4*)(of + (size_t)row*1024 + t*4) = o4;
  }
  if (ob){
    ushort4v u = { f2bs(y[0]), f2bs(y[1]), f2bs(y[2]), f2bs(y[3]) };
    *(ushort4v*)(ob + (size_t)row*1024 + t*4) = u;
  }
}

// ---------------- residual + LayerNorm (two bf16 partial sources) ----------------
__global__ __launch_bounds__(256) void ln_res2(const float* __restrict__ a,
                                               const unsigned short* __restrict__ p0,
                                               const unsigned short* __restrict__ p1,
                                               const float* __restrict__ g,
                                               const float* __restrict__ be,
                                               float* __restrict__ of){
  __shared__ float red1[4], red2[4];
  const int row = blockIdx.x, t = threadIdx.x;
  const int wave = t >> 6, lane = t & 63;
  const float4 va = *(const float4*)(a + (size_t)row*1024 + t*4);
  const ushort4v u0 = *(const ushort4v*)(p0 + (size_t)row*1024 + t*4);
  const ushort4v u1 = *(const ushort4v*)(p1 + (size_t)row*1024 + t*4);
  float xs[4] = { va.x + bs2f(u0[0]) + bs2f(u1[0]),
                  va.y + bs2f(u0[1]) + bs2f(u1[1]),
                  va.z + bs2f(u0[2]) + bs2f(u1[2]),
                  va.w + bs2f(u0[3]) + bs2f(u1[3]) };
  float s = xs[0]+xs[1]+xs[2]+xs[3];
  #pragma unroll
  for (int d=1; d<64; d<<=1) s += __shfl_xor(s, d, 64);
  if (lane==0) red1[wave] = s;
  __syncthreads();
  const float mean = (red1[0]+red1[1]+red1[2]+red1[3]) * (1.0f/1024.0f);
  float vsum = 0.0f;
  #pragma unroll
  for (int i=0;i<4;i++){ const float d = xs[i]-mean; vsum += d*d; }
  #pragma unroll
  for (int d=1; d<64; d<<=1) vsum += __shfl_xor(vsum, d, 64);
  if (lane==0) red2[wave] = vsum;
  __syncthreads();
  const float var = (red2[0]+red2[1]+red2[2]+red2[3]) * (1.0f/1024.0f);
  const float rs = rsqrtf(var + 1e-5f);
  const float4 gg = *(const float4*)(g + t*4);
  const float4 bb = *(const float4*)(be + t*4);
  float4 o4;
  o4.x = (xs[0]-mean)*rs*gg.x + bb.x;
  o4.y = (xs[1]-mean)*rs*gg.y + bb.y;
  o4.z = (xs[2]-mean)*rs*gg.z + bb.z;
  o4.w = (xs[3]-mean)*rs*gg.w + bb.w;
  *(float4*)(of + (size_t)row*1024 + t*4) = o4;
}

extern "C" void kernel_launch(void* const* d_in, const int* in_sizes, int n_in,
                              void* d_out, int out_size, void* d_ws, size_t ws_size,
                              hipStream_t stream){
  (void)in_sizes; (void)n_in; (void)out_size; (void)ws_size;
  const float* x  = (const float*)d_in[0];
  const float* wq = (const float*)d_in[1];
  const float* bq = (const float*)d_in[2];
  const float* wk = (const float*)d_in[3];
  const float* bk = (const float*)d_in[4];
  const float* wv = (const float*)d_in[5];
  const float* bv = (const float*)d_in[6];
  const float* wo = (const float*)d_in[7];
  const float* bo = (const float*)d_in[8];
  const float* w1 = (const float*)d_in[9];
  const float* b1 = (const float*)d_in[10];
  const float* w2 = (const float*)d_in[11];
  const float* b2 = (const float*)d_in[12];
  const float* g1 = (const float*)d_in[13];
  const float* be1= (const float*)d_in[14];
  const float* g2 = (const float*)d_in[15];
  const float* be2= (const float*)d_in[16];
  float* out = (float*)d_out;

  char* ws = (char*)d_ws;
  size_t off = 0;
  auto take = [&](size_t bytes)->char*{
    char* p = ws + off; off += (bytes + 255) & ~(size_t)255; return p;
  };
  unsigned short* Xb  = (unsigned short*)take(8192UL*1024*2);
  unsigned short* Qb  = (unsigned short*)take(8192UL*1024*2);
  unsigned short* Kb  = (unsigned short*)take(8192UL*1024*2);
  unsigned short* Vtb = (unsigned short*)take(8192UL*1024*2);
  unsigned short* Ob  = (unsigned short*)take(8192UL*1024*2);
  unsigned short* Midb= Qb;                    // alias: spans Qb..Ob (64 MB), dead by FFN1
  unsigned short* Vtok= (unsigned short*)take(8192UL*1024*2);
  unsigned short* Wqkv= (unsigned short*)take(3072UL*1024*2);
  float*          Bqkv= (float*)take(3072UL*4);
  unsigned short* Wot = (unsigned short*)take(1024UL*1024*2);
  unsigned short* W1t = (unsigned short*)take(4096UL*1024*2);
  unsigned short* W2t = (unsigned short*)take(1024UL*4096*2);
  float*          C1  = (float*)take(8192UL*1024*4);
  unsigned short* F0  = (unsigned short*)C1;   // alias: C1 dead after LN1; F0+F1 = 32 MB
  unsigned short* F1  = F0 + 8192UL*1024;
  float*          Hf  = (float*)take(8192UL*1024*4);
  unsigned short* Hb  = (unsigned short*)take(8192UL*1024*2);

  // 1. fused prep: cvt_x + pack_qkv + 3x transpose_pack (one launch)
  prep<<<14336, 256, 0, stream>>>(x, Xb, wq, wk, wv, bq, bk, bv,
                                  Wqkv, Bqkv, wo, Wot, w1, W1t, w2, W2t);

  // 2. fused QKV projection + V transpose
  gemm256<3><<<12*32, 512, 0, stream>>>(Wqkv, Xb, Bqkv, Qb, Kb, Vtok, 1024, 1024);
  vtrans<<<dim3(32,64), 256, 0, stream>>>(Vtok, Vtb);

  // 3. causal flash attention (gl_lds staging, fixed-max softmax, 4 blocks/CU)
  attn<<<1024, 256, 0, stream>>>(Qb, Kb, Vtb, Ob);

  // 4. output projection (fp32, 128^2 kernel) -> residual + LN1
  gemm_tn<1><<<8*64, 256, 0, stream>>>(Wot, Ob, bo, C1, nullptr, nullptr, 1024, 1024, 1024);
  ln_res<<<8192, 256, 0, stream>>>(x, C1, g1, be1, Hf, Hb);

  // 5. FFN: gelu(h@w1+b1) -> Midb; w2 split-K x2 -> bf16 partials
  gemm256<2><<<16*32, 512, 0, stream>>>(W1t, Hb, b1, Midb, nullptr, nullptr, 1024, 1024);
  gemm256<4><<<dim3(4*32,1,2), 512, 0, stream>>>(W2t, Midb, b2, F0, F1, nullptr, 4096, 2048);
  ln_res2<<<8192, 256, 0, stream>>>(Hf, F0, F1, g2, be2, out);
}